// Round 2
// baseline (1372.458 us; speedup 1.0000x reference)
//
#include <hip/hip_runtime.h>
#include <hip/hip_bf16.h>

// GCN 2-layer forward, fp32 I/O. Pipeline:
//  1) deg[i] = 1 (self loop) + #edges with dst==i ; dinv = rsqrt(deg)
//  2) h1 = x @ W1
//  3) agg1[i] = h1[i]*dinv[i]^2 ; agg1[dst] += h1[src]*dinv[src]*dinv[dst]
//  4) h2 = relu(agg1 + b1) @ W2
//  5) agg2 same as (3) with 64 feats
//  6) out = agg2 + b2
// Workspace (fp32): dinv[N] | bufH[N*128] | bufA[N*128]  (~103 MB)

__global__ void k_fill1(float* __restrict__ deg, int n) {
    int i = blockIdx.x * blockDim.x + threadIdx.x;
    if (i < n) deg[i] = 1.0f;   // self-loop contributes 1 to every degree
}

__global__ void k_deg(const int* __restrict__ dst, float* __restrict__ deg, int E) {
    int e = blockIdx.x * blockDim.x + threadIdx.x;
    if (e < E) atomicAdd(&deg[dst[e]], 1.0f);
}

__global__ void k_rsqrt(float* __restrict__ deg, int n) {
    int i = blockIdx.x * blockDim.x + threadIdx.x;
    if (i < n) deg[i] = rsqrtf(deg[i]);   // deg >= 1 always
}

// h[n,128] = x[n,128] @ W[128,128]. 8 rows/block, 256 threads.
// x-tile staged in LDS (4 KB), W streamed from global (64 KB, L1/L2-hot).
// Thread layout: j = tid&127 (out col), rh = tid>>7 selects 4-row group.
__global__ __launch_bounds__(256) void k_gemm1(const float* __restrict__ x,
                                               const float* __restrict__ W,
                                               float* __restrict__ h, int nrows) {
    __shared__ float xs[8 * 128];
    int tid = threadIdx.x;
    int row0 = blockIdx.x * 8;
    for (int i = tid; i < 8 * 128; i += 256) {
        int r = row0 + (i >> 7);
        xs[i] = (r < nrows) ? x[(size_t)r * 128 + (i & 127)] : 0.0f;
    }
    __syncthreads();
    int j  = tid & 127;
    int rh = tid >> 7;
    const float4* xr = (const float4*)&xs[rh * 4 * 128];   // 4 rows, 32 float4 each
    float a0 = 0.f, a1 = 0.f, a2 = 0.f, a3 = 0.f;
    #pragma unroll 8
    for (int k4 = 0; k4 < 32; ++k4) {
        float4 x0 = xr[0 * 32 + k4];
        float4 x1 = xr[1 * 32 + k4];
        float4 x2 = xr[2 * 32 + k4];
        float4 x3 = xr[3 * 32 + k4];
        float w0 = W[(k4 * 4 + 0) * 128 + j];
        float w1 = W[(k4 * 4 + 1) * 128 + j];
        float w2 = W[(k4 * 4 + 2) * 128 + j];
        float w3 = W[(k4 * 4 + 3) * 128 + j];
        a0 += x0.x * w0 + x0.y * w1 + x0.z * w2 + x0.w * w3;
        a1 += x1.x * w0 + x1.y * w1 + x1.z * w2 + x1.w * w3;
        a2 += x2.x * w0 + x2.y * w1 + x2.z * w2 + x2.w * w3;
        a3 += x3.x * w0 + x3.y * w1 + x3.z * w2 + x3.w * w3;
    }
    int rb = row0 + rh * 4;
    if (rb + 0 < nrows) h[(size_t)(rb + 0) * 128 + j] = a0;
    if (rb + 1 < nrows) h[(size_t)(rb + 1) * 128 + j] = a1;
    if (rb + 2 < nrows) h[(size_t)(rb + 2) * 128 + j] = a2;
    if (rb + 3 < nrows) h[(size_t)(rb + 3) * 128 + j] = a3;
}

// h2[n,64] = relu(a[n,128] + b1) @ W[128,64]. 16 rows/block, 256 threads.
__global__ __launch_bounds__(256) void k_gemm2(const float* __restrict__ a,
                                               const float* __restrict__ b1,
                                               const float* __restrict__ W,
                                               float* __restrict__ h2, int nrows) {
    __shared__ float xs[16 * 128];
    int tid = threadIdx.x;
    int row0 = blockIdx.x * 16;
    for (int i = tid; i < 16 * 128; i += 256) {
        int r = row0 + (i >> 7);
        int c = i & 127;
        float v = 0.0f;
        if (r < nrows) v = fmaxf(a[(size_t)r * 128 + c] + b1[c], 0.0f);  // +bias, relu
        xs[i] = v;
    }
    __syncthreads();
    int j = tid & 63;         // out col
    int q = tid >> 6;         // 4-row group
    const float4* xr = (const float4*)&xs[q * 4 * 128];
    float a0 = 0.f, a1 = 0.f, a2 = 0.f, a3 = 0.f;
    #pragma unroll 8
    for (int k4 = 0; k4 < 32; ++k4) {
        float4 x0 = xr[0 * 32 + k4];
        float4 x1 = xr[1 * 32 + k4];
        float4 x2 = xr[2 * 32 + k4];
        float4 x3 = xr[3 * 32 + k4];
        float w0 = W[(k4 * 4 + 0) * 64 + j];
        float w1 = W[(k4 * 4 + 1) * 64 + j];
        float w2 = W[(k4 * 4 + 2) * 64 + j];
        float w3 = W[(k4 * 4 + 3) * 64 + j];
        a0 += x0.x * w0 + x0.y * w1 + x0.z * w2 + x0.w * w3;
        a1 += x1.x * w0 + x1.y * w1 + x1.z * w2 + x1.w * w3;
        a2 += x2.x * w0 + x2.y * w1 + x2.z * w2 + x2.w * w3;
        a3 += x3.x * w0 + x3.y * w1 + x3.z * w2 + x3.w * w3;
    }
    int rb = row0 + q * 4;
    if (rb + 0 < nrows) h2[(size_t)(rb + 0) * 64 + j] = a0;
    if (rb + 1 < nrows) h2[(size_t)(rb + 1) * 64 + j] = a1;
    if (rb + 2 < nrows) h2[(size_t)(rb + 2) * 64 + j] = a2;
    if (rb + 3 < nrows) h2[(size_t)(rb + 3) * 64 + j] = a3;
}

// agg init with self-loop term: agg[i,f] = h[i,f] * dinv[i]^2
__global__ void k_self128(const float* __restrict__ h, const float* __restrict__ dinv,
                          float* __restrict__ agg, int total) {
    int i = blockIdx.x * blockDim.x + threadIdx.x;
    if (i < total) { float d = dinv[i >> 7]; agg[i] = h[i] * d * d; }
}
__global__ void k_self64(const float* __restrict__ h, const float* __restrict__ dinv,
                         float* __restrict__ agg, int total) {
    int i = blockIdx.x * blockDim.x + threadIdx.x;
    if (i < total) { float d = dinv[i >> 6]; agg[i] = h[i] * d * d; }
}

// edge scatter: agg[dst,f] += h[src,f]*dinv[src]*dinv[dst]
__global__ void k_agg128(const float* __restrict__ h, const int* __restrict__ src,
                         const int* __restrict__ dst, const float* __restrict__ dinv,
                         float* __restrict__ agg, int E) {
    int idx = blockIdx.x * blockDim.x + threadIdx.x;
    int e = idx >> 7;                 // 128 lanes per edge (wave-uniform e)
    if (e >= E) return;
    int f = idx & 127;
    int s = src[e], d = dst[e];
    float nrm = dinv[s] * dinv[d];
    atomicAdd(&agg[d * 128 + f], h[s * 128 + f] * nrm);
}
__global__ void k_agg64(const float* __restrict__ h, const int* __restrict__ src,
                        const int* __restrict__ dst, const float* __restrict__ dinv,
                        float* __restrict__ agg, int E) {
    int idx = blockIdx.x * blockDim.x + threadIdx.x;
    int e = idx >> 6;                 // 64 lanes per edge
    if (e >= E) return;
    int f = idx & 63;
    int s = src[e], d = dst[e];
    float nrm = dinv[s] * dinv[d];
    atomicAdd(&agg[d * 64 + f], h[s * 64 + f] * nrm);
}

__global__ void k_out(const float* __restrict__ agg, const float* __restrict__ b,
                      float* __restrict__ out, int total) {
    int i = blockIdx.x * blockDim.x + threadIdx.x;
    if (i < total) out[i] = agg[i] + b[i & 63];
}

extern "C" void kernel_launch(void* const* d_in, const int* in_sizes, int n_in,
                              void* d_out, int out_size, void* d_ws, size_t ws_size,
                              hipStream_t stream) {
    const float* x  = (const float*)d_in[0];
    const int*   ei = (const int*)d_in[1];
    const float* W1 = (const float*)d_in[2];
    const float* b1 = (const float*)d_in[3];
    const float* W2 = (const float*)d_in[4];
    const float* b2 = (const float*)d_in[5];
    float* out = (float*)d_out;

    const int N = in_sizes[0] / 128;
    const int E = in_sizes[1] / 2;
    const int* src = ei;
    const int* dst = ei + E;

    float* dinv = (float*)d_ws;                    // N floats
    float* bufH = dinv + N;                        // N*128 floats
    float* bufA = bufH + (size_t)N * 128;          // N*128 floats

    // normalization coefficients
    k_fill1<<<(N + 255) / 256, 256, 0, stream>>>(dinv, N);
    k_deg<<<(E + 255) / 256, 256, 0, stream>>>(dst, dinv, E);
    k_rsqrt<<<(N + 255) / 256, 256, 0, stream>>>(dinv, N);

    // layer 1
    k_gemm1<<<(N + 7) / 8, 256, 0, stream>>>(x, W1, bufH, N);
    {
        int total = N * 128;
        k_self128<<<(total + 255) / 256, 256, 0, stream>>>(bufH, dinv, bufA, total);
        long long t = (long long)E * 128;
        k_agg128<<<(int)((t + 255) / 256), 256, 0, stream>>>(bufH, src, dst, dinv, bufA, E);
    }

    // layer 2
    k_gemm2<<<(N + 15) / 16, 256, 0, stream>>>(bufA, b1, W2, bufH, N);
    {
        int total = N * 64;
        k_self64<<<(total + 255) / 256, 256, 0, stream>>>(bufH, dinv, bufA, total);
        long long t = (long long)E * 64;
        k_agg64<<<(int)((t + 255) / 256), 256, 0, stream>>>(bufH, src, dst, dinv, bufA, E);
        k_out<<<(total + 255) / 256, 256, 0, stream>>>(bufA, b2, out, total);
    }
}

// Round 3
// 620.973 us; speedup vs baseline: 2.2102x; 2.2102x over previous
//
#include <hip/hip_runtime.h>
#include <hip/hip_bf16.h>

// GCN 2-layer forward, fp32 I/O, atomic-free aggregation via device-built CSR.
// Pipeline:
//  1) deg[i] = #edges with dst==i ; dinv = rsqrt(deg+1)   (self-loop)
//  2) CSR build: exclusive scan of deg -> row_ptr; bucket-scatter src ids
//  3) h1 = x @ W1                                  (k_gemm1)
//  4) agg1[i] = dinv[i]^2*h1[i] + sum_e dinv[i]*dinv[s]*h1[s]   (k_pull128)
//  5) h2 = relu(agg1 + b1) @ W2                    (k_gemm2)
//  6) out[i] = pull-aggregate(h2) + b2             (k_pull64, fused bias)
// Workspace: dinv[N]f | deg[N]i | row_ptr[N]i | cursor[N]i | bsum[1024]i |
//            csr[E]i | bufH[N*128]f | bufA[N*128]f   (~111 MB)

__global__ void k_zero(int* __restrict__ p, int n) {
    int i = blockIdx.x * blockDim.x + threadIdx.x;
    if (i < n) p[i] = 0;
}

__global__ void k_deg(const int* __restrict__ dst, int* __restrict__ deg, int E) {
    int e = blockIdx.x * blockDim.x + threadIdx.x;
    if (e < E) atomicAdd(&deg[dst[e]], 1);
}

// per-256-block exclusive scan; block sums to bsum
__global__ __launch_bounds__(256) void k_scan1(const int* __restrict__ deg,
                                               int* __restrict__ row_ptr,
                                               int* __restrict__ bsum, int n) {
    __shared__ int s[256];
    int t = threadIdx.x;
    int i = blockIdx.x * 256 + t;
    int v = (i < n) ? deg[i] : 0;
    s[t] = v;
    __syncthreads();
    for (int off = 1; off < 256; off <<= 1) {
        int add = (t >= off) ? s[t - off] : 0;
        __syncthreads();
        s[t] += add;
        __syncthreads();
    }
    if (i < n) row_ptr[i] = s[t] - v;           // exclusive
    if (t == 255) bsum[blockIdx.x] = s[255];
}

// single-block exclusive scan of block sums (nb <= 1024)
__global__ __launch_bounds__(1024) void k_scan2(int* __restrict__ bsum, int nb) {
    __shared__ int s[1024];
    int t = threadIdx.x;
    int v = (t < nb) ? bsum[t] : 0;
    s[t] = v;
    __syncthreads();
    for (int off = 1; off < 1024; off <<= 1) {
        int add = (t >= off) ? s[t - off] : 0;
        __syncthreads();
        s[t] += add;
        __syncthreads();
    }
    if (t < nb) bsum[t] = s[t] - v;             // exclusive
}

// add block offsets; init cursor; dinv = rsqrt(deg+1)
__global__ void k_scan3(int* __restrict__ row_ptr, const int* __restrict__ bsum,
                        const int* __restrict__ deg, int* __restrict__ cursor,
                        float* __restrict__ dinv, int n) {
    int i = blockIdx.x * blockDim.x + threadIdx.x;
    if (i >= n) return;
    int rp = row_ptr[i] + bsum[i >> 8];
    row_ptr[i] = rp;
    cursor[i]  = rp;
    dinv[i] = rsqrtf((float)(deg[i] + 1));
}

__global__ void k_scatter(const int* __restrict__ src, const int* __restrict__ dst,
                          int* __restrict__ cursor, int* __restrict__ csr, int E) {
    int e = blockIdx.x * blockDim.x + threadIdx.x;
    if (e < E) {
        int pos = atomicAdd(&cursor[dst[e]], 1);
        csr[pos] = src[e];
    }
}

// h[n,128] = x[n,128] @ W[128,128]. 8 rows/block, 256 threads.
__global__ __launch_bounds__(256) void k_gemm1(const float* __restrict__ x,
                                               const float* __restrict__ W,
                                               float* __restrict__ h, int nrows) {
    __shared__ float xs[8 * 128];
    int tid = threadIdx.x;
    int row0 = blockIdx.x * 8;
    for (int i = tid; i < 8 * 128; i += 256) {
        int r = row0 + (i >> 7);
        xs[i] = (r < nrows) ? x[(size_t)r * 128 + (i & 127)] : 0.0f;
    }
    __syncthreads();
    int j  = tid & 127;
    int rh = tid >> 7;
    const float4* xr = (const float4*)&xs[rh * 4 * 128];
    float a0 = 0.f, a1 = 0.f, a2 = 0.f, a3 = 0.f;
    #pragma unroll 8
    for (int k4 = 0; k4 < 32; ++k4) {
        float4 x0 = xr[0 * 32 + k4];
        float4 x1 = xr[1 * 32 + k4];
        float4 x2 = xr[2 * 32 + k4];
        float4 x3 = xr[3 * 32 + k4];
        float w0 = W[(k4 * 4 + 0) * 128 + j];
        float w1 = W[(k4 * 4 + 1) * 128 + j];
        float w2 = W[(k4 * 4 + 2) * 128 + j];
        float w3 = W[(k4 * 4 + 3) * 128 + j];
        a0 += x0.x * w0 + x0.y * w1 + x0.z * w2 + x0.w * w3;
        a1 += x1.x * w0 + x1.y * w1 + x1.z * w2 + x1.w * w3;
        a2 += x2.x * w0 + x2.y * w1 + x2.z * w2 + x2.w * w3;
        a3 += x3.x * w0 + x3.y * w1 + x3.z * w2 + x3.w * w3;
    }
    int rb = row0 + rh * 4;
    if (rb + 0 < nrows) h[(size_t)(rb + 0) * 128 + j] = a0;
    if (rb + 1 < nrows) h[(size_t)(rb + 1) * 128 + j] = a1;
    if (rb + 2 < nrows) h[(size_t)(rb + 2) * 128 + j] = a2;
    if (rb + 3 < nrows) h[(size_t)(rb + 3) * 128 + j] = a3;
}

// h2[n,64] = relu(a[n,128] + b1) @ W[128,64]. 16 rows/block, 256 threads.
__global__ __launch_bounds__(256) void k_gemm2(const float* __restrict__ a,
                                               const float* __restrict__ b1,
                                               const float* __restrict__ W,
                                               float* __restrict__ h2, int nrows) {
    __shared__ float xs[16 * 128];
    int tid = threadIdx.x;
    int row0 = blockIdx.x * 16;
    for (int i = tid; i < 16 * 128; i += 256) {
        int r = row0 + (i >> 7);
        int c = i & 127;
        float v = 0.0f;
        if (r < nrows) v = fmaxf(a[(size_t)r * 128 + c] + b1[c], 0.0f);
        xs[i] = v;
    }
    __syncthreads();
    int j = tid & 63;
    int q = tid >> 6;
    const float4* xr = (const float4*)&xs[q * 4 * 128];
    float a0 = 0.f, a1 = 0.f, a2 = 0.f, a3 = 0.f;
    #pragma unroll 8
    for (int k4 = 0; k4 < 32; ++k4) {
        float4 x0 = xr[0 * 32 + k4];
        float4 x1 = xr[1 * 32 + k4];
        float4 x2 = xr[2 * 32 + k4];
        float4 x3 = xr[3 * 32 + k4];
        float w0 = W[(k4 * 4 + 0) * 64 + j];
        float w1 = W[(k4 * 4 + 1) * 64 + j];
        float w2 = W[(k4 * 4 + 2) * 64 + j];
        float w3 = W[(k4 * 4 + 3) * 64 + j];
        a0 += x0.x * w0 + x0.y * w1 + x0.z * w2 + x0.w * w3;
        a1 += x1.x * w0 + x1.y * w1 + x1.z * w2 + x1.w * w3;
        a2 += x2.x * w0 + x2.y * w1 + x2.z * w2 + x2.w * w3;
        a3 += x3.x * w0 + x3.y * w1 + x3.z * w2 + x3.w * w3;
    }
    int rb = row0 + q * 4;
    if (rb + 0 < nrows) h2[(size_t)(rb + 0) * 64 + j] = a0;
    if (rb + 1 < nrows) h2[(size_t)(rb + 1) * 64 + j] = a1;
    if (rb + 2 < nrows) h2[(size_t)(rb + 2) * 64 + j] = a2;
    if (rb + 3 < nrows) h2[(size_t)(rb + 3) * 64 + j] = a3;
}

// pull aggregation, 128 feats: one wave per node, lane owns feats [2l,2l+1].
__global__ __launch_bounds__(256) void k_pull128(const float* __restrict__ h,
                                                 const int* __restrict__ row_ptr,
                                                 const int* __restrict__ deg,
                                                 const int* __restrict__ csr,
                                                 const float* __restrict__ dinv,
                                                 float* __restrict__ agg, int n) {
    int wave = (blockIdx.x * 256 + threadIdx.x) >> 6;
    int lane = threadIdx.x & 63;
    if (wave >= n) return;
    int i = __builtin_amdgcn_readfirstlane(wave);   // scalarize node index
    float di = dinv[i];
    float2 acc;
    {
        float2 v = ((const float2*)&h[(size_t)i * 128])[lane];
        float w = di * di;                           // self-loop norm
        acc.x = v.x * w; acc.y = v.y * w;
    }
    int beg = row_ptr[i];
    int cnt = deg[i];
    int k = 0;
    for (; k + 4 <= cnt; k += 4) {                  // 4-wide MLP unroll
        int s0 = csr[beg + k + 0];
        int s1 = csr[beg + k + 1];
        int s2 = csr[beg + k + 2];
        int s3 = csr[beg + k + 3];
        float n0 = di * dinv[s0], n1 = di * dinv[s1];
        float n2 = di * dinv[s2], n3 = di * dinv[s3];
        float2 v0 = ((const float2*)&h[(size_t)s0 * 128])[lane];
        float2 v1 = ((const float2*)&h[(size_t)s1 * 128])[lane];
        float2 v2 = ((const float2*)&h[(size_t)s2 * 128])[lane];
        float2 v3 = ((const float2*)&h[(size_t)s3 * 128])[lane];
        acc.x += v0.x * n0 + v1.x * n1 + v2.x * n2 + v3.x * n3;
        acc.y += v0.y * n0 + v1.y * n1 + v2.y * n2 + v3.y * n3;
    }
    for (; k < cnt; ++k) {
        int s = csr[beg + k];
        float nrm = di * dinv[s];
        float2 v = ((const float2*)&h[(size_t)s * 128])[lane];
        acc.x += v.x * nrm; acc.y += v.y * nrm;
    }
    ((float2*)&agg[(size_t)i * 128])[lane] = acc;
}

// pull aggregation, 64 feats, fused +b2 -> out
__global__ __launch_bounds__(256) void k_pull64(const float* __restrict__ h,
                                                const int* __restrict__ row_ptr,
                                                const int* __restrict__ deg,
                                                const int* __restrict__ csr,
                                                const float* __restrict__ dinv,
                                                const float* __restrict__ b2,
                                                float* __restrict__ out, int n) {
    int wave = (blockIdx.x * 256 + threadIdx.x) >> 6;
    int lane = threadIdx.x & 63;
    if (wave >= n) return;
    int i = __builtin_amdgcn_readfirstlane(wave);
    float di = dinv[i];
    float acc = h[(size_t)i * 64 + lane] * di * di;
    int beg = row_ptr[i];
    int cnt = deg[i];
    int k = 0;
    for (; k + 4 <= cnt; k += 4) {
        int s0 = csr[beg + k + 0];
        int s1 = csr[beg + k + 1];
        int s2 = csr[beg + k + 2];
        int s3 = csr[beg + k + 3];
        float n0 = di * dinv[s0], n1 = di * dinv[s1];
        float n2 = di * dinv[s2], n3 = di * dinv[s3];
        acc += h[(size_t)s0 * 64 + lane] * n0 + h[(size_t)s1 * 64 + lane] * n1
             + h[(size_t)s2 * 64 + lane] * n2 + h[(size_t)s3 * 64 + lane] * n3;
    }
    for (; k < cnt; ++k) {
        int s = csr[beg + k];
        acc += h[(size_t)s * 64 + lane] * (di * dinv[s]);
    }
    out[(size_t)i * 64 + lane] = acc + b2[lane];
}

extern "C" void kernel_launch(void* const* d_in, const int* in_sizes, int n_in,
                              void* d_out, int out_size, void* d_ws, size_t ws_size,
                              hipStream_t stream) {
    const float* x  = (const float*)d_in[0];
    const int*   ei = (const int*)d_in[1];
    const float* W1 = (const float*)d_in[2];
    const float* b1 = (const float*)d_in[3];
    const float* W2 = (const float*)d_in[4];
    const float* b2 = (const float*)d_in[5];
    float* out = (float*)d_out;

    const int N = in_sizes[0] / 128;
    const int E = in_sizes[1] / 2;
    const int* src = ei;
    const int* dst = ei + E;

    float* dinv    = (float*)d_ws;                 // N
    int*   deg     = (int*)(dinv + N);             // N
    int*   row_ptr = deg + N;                      // N
    int*   cursor  = row_ptr + N;                  // N
    int*   bsum    = cursor + N;                   // 1024
    int*   csr     = bsum + 1024;                  // E
    float* bufH    = (float*)(csr + E);            // N*128
    float* bufA    = bufH + (size_t)N * 128;       // N*128

    const int nb = (N + 255) / 256;                // scan blocks (391 <= 1024)

    // ---- CSR build + normalization ----
    k_zero<<<(N + 255) / 256, 256, 0, stream>>>(deg, N);
    k_deg<<<(E + 255) / 256, 256, 0, stream>>>(dst, deg, E);
    k_scan1<<<nb, 256, 0, stream>>>(deg, row_ptr, bsum, N);
    k_scan2<<<1, 1024, 0, stream>>>(bsum, nb);
    k_scan3<<<(N + 255) / 256, 256, 0, stream>>>(row_ptr, bsum, deg, cursor, dinv, N);
    k_scatter<<<(E + 255) / 256, 256, 0, stream>>>(src, dst, cursor, csr, E);

    // ---- layer 1 ----
    k_gemm1<<<(N + 7) / 8, 256, 0, stream>>>(x, W1, bufH, N);
    k_pull128<<<(N + 3) / 4, 256, 0, stream>>>(bufH, row_ptr, deg, csr, dinv, bufA, N);

    // ---- layer 2 ----
    k_gemm2<<<(N + 15) / 16, 256, 0, stream>>>(bufA, b1, W2, bufH, N);
    k_pull64<<<(N + 3) / 4, 256, 0, stream>>>(bufH, row_ptr, deg, csr, dinv, b2, out, N);
}

// Round 4
// 517.131 us; speedup vs baseline: 2.6540x; 1.2008x over previous
//
#include <hip/hip_runtime.h>
#include <hip/hip_bf16.h>

// GCN 2-layer forward, fp32 I/O. CSR pull aggregation; h1/h2 stored bf16;
// csr entry = {src, dinv[src]} so pulls do zero scattered dinv reads.
// Pipeline:
//  1) deg histogram; hierarchical scan -> row_ptr; dinv = rsqrt(deg+1)
//  2) scatter: csr8[pos] = {src, dinv[src]}
//  3) h1 = x @ W1 -> bf16                          (k_gemm1)
//  4) agg1 = D^-1/2 (A+I) D^-1/2 h1 -> fp32        (k_pull128)
//  5) h2 = relu(agg1 + b1) @ W2 -> bf16            (k_gemm2)
//  6) out = aggregate(h2) + b2 -> fp32             (k_pull64)
// Workspace: dinv[N]f | deg[N]i | row_ptr[N]i | cursor[N]i | bsum[1024]i |
//            csr8[E]int2 | bufH[N*128]bf16 | bufA[N*128]f   (~91 MB)

__global__ void k_zero(int* __restrict__ p, int n) {
    int i = blockIdx.x * blockDim.x + threadIdx.x;
    if (i < n) p[i] = 0;
}

__global__ void k_deg(const int* __restrict__ dst, int* __restrict__ deg, int E) {
    int e = blockIdx.x * blockDim.x + threadIdx.x;
    if (e < E) atomicAdd(&deg[dst[e]], 1);
}

// per-256-block exclusive scan; block sums to bsum
__global__ __launch_bounds__(256) void k_scan1(const int* __restrict__ deg,
                                               int* __restrict__ row_ptr,
                                               int* __restrict__ bsum, int n) {
    __shared__ int s[256];
    int t = threadIdx.x;
    int i = blockIdx.x * 256 + t;
    int v = (i < n) ? deg[i] : 0;
    s[t] = v;
    __syncthreads();
    for (int off = 1; off < 256; off <<= 1) {
        int add = (t >= off) ? s[t - off] : 0;
        __syncthreads();
        s[t] += add;
        __syncthreads();
    }
    if (i < n) row_ptr[i] = s[t] - v;           // exclusive
    if (t == 255) bsum[blockIdx.x] = s[255];
}

// single-block exclusive scan of block sums (nb <= 1024)
__global__ __launch_bounds__(1024) void k_scan2(int* __restrict__ bsum, int nb) {
    __shared__ int s[1024];
    int t = threadIdx.x;
    int v = (t < nb) ? bsum[t] : 0;
    s[t] = v;
    __syncthreads();
    for (int off = 1; off < 1024; off <<= 1) {
        int add = (t >= off) ? s[t - off] : 0;
        __syncthreads();
        s[t] += add;
        __syncthreads();
    }
    if (t < nb) bsum[t] = s[t] - v;             // exclusive
}

// add block offsets; init cursor; dinv = rsqrt(deg+1)
__global__ void k_scan3(int* __restrict__ row_ptr, const int* __restrict__ bsum,
                        const int* __restrict__ deg, int* __restrict__ cursor,
                        float* __restrict__ dinv, int n) {
    int i = blockIdx.x * blockDim.x + threadIdx.x;
    if (i >= n) return;
    int rp = row_ptr[i] + bsum[i >> 8];
    row_ptr[i] = rp;
    cursor[i]  = rp;
    dinv[i] = rsqrtf((float)(deg[i] + 1));
}

// csr8[pos] = {src, dinv[src]} — random-write-BW bound; dinv gather rides free
__global__ void k_scatter(const int* __restrict__ src, const int* __restrict__ dst,
                          int* __restrict__ cursor, const float* __restrict__ dinv,
                          int2* __restrict__ csr8, int E) {
    int e = blockIdx.x * blockDim.x + threadIdx.x;
    if (e < E) {
        int s = src[e];
        int pos = atomicAdd(&cursor[dst[e]], 1);
        csr8[pos] = make_int2(s, __float_as_int(dinv[s]));
    }
}

// h[n,128] = x[n,128] @ W[128,128] -> bf16. 8 rows/block, 256 threads.
__global__ __launch_bounds__(256) void k_gemm1(const float* __restrict__ x,
                                               const float* __restrict__ W,
                                               __hip_bfloat16* __restrict__ h, int nrows) {
    __shared__ float xs[8 * 128];
    int tid = threadIdx.x;
    int row0 = blockIdx.x * 8;
    for (int i = tid; i < 8 * 128; i += 256) {
        int r = row0 + (i >> 7);
        xs[i] = (r < nrows) ? x[(size_t)r * 128 + (i & 127)] : 0.0f;
    }
    __syncthreads();
    int j  = tid & 127;
    int rh = tid >> 7;
    const float4* xr = (const float4*)&xs[rh * 4 * 128];
    float a0 = 0.f, a1 = 0.f, a2 = 0.f, a3 = 0.f;
    #pragma unroll 8
    for (int k4 = 0; k4 < 32; ++k4) {
        float4 x0 = xr[0 * 32 + k4];
        float4 x1 = xr[1 * 32 + k4];
        float4 x2 = xr[2 * 32 + k4];
        float4 x3 = xr[3 * 32 + k4];
        float w0 = W[(k4 * 4 + 0) * 128 + j];
        float w1 = W[(k4 * 4 + 1) * 128 + j];
        float w2 = W[(k4 * 4 + 2) * 128 + j];
        float w3 = W[(k4 * 4 + 3) * 128 + j];
        a0 += x0.x * w0 + x0.y * w1 + x0.z * w2 + x0.w * w3;
        a1 += x1.x * w0 + x1.y * w1 + x1.z * w2 + x1.w * w3;
        a2 += x2.x * w0 + x2.y * w1 + x2.z * w2 + x2.w * w3;
        a3 += x3.x * w0 + x3.y * w1 + x3.z * w2 + x3.w * w3;
    }
    int rb = row0 + rh * 4;
    if (rb + 0 < nrows) h[(size_t)(rb + 0) * 128 + j] = __float2bfloat16(a0);
    if (rb + 1 < nrows) h[(size_t)(rb + 1) * 128 + j] = __float2bfloat16(a1);
    if (rb + 2 < nrows) h[(size_t)(rb + 2) * 128 + j] = __float2bfloat16(a2);
    if (rb + 3 < nrows) h[(size_t)(rb + 3) * 128 + j] = __float2bfloat16(a3);
}

// h2[n,64] = relu(a[n,128] + b1) @ W[128,64] -> bf16. 16 rows/block.
__global__ __launch_bounds__(256) void k_gemm2(const float* __restrict__ a,
                                               const float* __restrict__ b1,
                                               const float* __restrict__ W,
                                               __hip_bfloat16* __restrict__ h2, int nrows) {
    __shared__ float xs[16 * 128];
    int tid = threadIdx.x;
    int row0 = blockIdx.x * 16;
    for (int i = tid; i < 16 * 128; i += 256) {
        int r = row0 + (i >> 7);
        int c = i & 127;
        float v = 0.0f;
        if (r < nrows) v = fmaxf(a[(size_t)r * 128 + c] + b1[c], 0.0f);
        xs[i] = v;
    }
    __syncthreads();
    int j = tid & 63;
    int q = tid >> 6;
    const float4* xr = (const float4*)&xs[q * 4 * 128];
    float a0 = 0.f, a1 = 0.f, a2 = 0.f, a3 = 0.f;
    #pragma unroll 8
    for (int k4 = 0; k4 < 32; ++k4) {
        float4 x0 = xr[0 * 32 + k4];
        float4 x1 = xr[1 * 32 + k4];
        float4 x2 = xr[2 * 32 + k4];
        float4 x3 = xr[3 * 32 + k4];
        float w0 = W[(k4 * 4 + 0) * 64 + j];
        float w1 = W[(k4 * 4 + 1) * 64 + j];
        float w2 = W[(k4 * 4 + 2) * 64 + j];
        float w3 = W[(k4 * 4 + 3) * 64 + j];
        a0 += x0.x * w0 + x0.y * w1 + x0.z * w2 + x0.w * w3;
        a1 += x1.x * w0 + x1.y * w1 + x1.z * w2 + x1.w * w3;
        a2 += x2.x * w0 + x2.y * w1 + x2.z * w2 + x2.w * w3;
        a3 += x3.x * w0 + x3.y * w1 + x3.z * w2 + x3.w * w3;
    }
    int rb = row0 + q * 4;
    if (rb + 0 < nrows) h2[(size_t)(rb + 0) * 64 + j] = __float2bfloat16(a0);
    if (rb + 1 < nrows) h2[(size_t)(rb + 1) * 64 + j] = __float2bfloat16(a1);
    if (rb + 2 < nrows) h2[(size_t)(rb + 2) * 64 + j] = __float2bfloat16(a2);
    if (rb + 3 < nrows) h2[(size_t)(rb + 3) * 64 + j] = __float2bfloat16(a3);
}

__device__ __forceinline__ float bf_lo(unsigned u) { return __uint_as_float(u << 16); }
__device__ __forceinline__ float bf_hi(unsigned u) { return __uint_as_float(u & 0xffff0000u); }

// pull aggregation, 128 bf16 feats: one wave/node, lane owns feats [2l,2l+1].
__global__ __launch_bounds__(256) void k_pull128(const __hip_bfloat16* __restrict__ h,
                                                 const int* __restrict__ row_ptr,
                                                 const int* __restrict__ deg,
                                                 const int2* __restrict__ csr8,
                                                 const float* __restrict__ dinv,
                                                 float* __restrict__ agg, int n) {
    int wave = (blockIdx.x * 256 + threadIdx.x) >> 6;
    int lane = threadIdx.x & 63;
    if (wave >= n) return;
    int i = __builtin_amdgcn_readfirstlane(wave);
    float di = dinv[i];
    float2 acc;
    {
        unsigned u = ((const unsigned*)(h + (size_t)i * 128))[lane];
        float w = di * di;                            // self-loop norm
        acc.x = bf_lo(u) * w; acc.y = bf_hi(u) * w;
    }
    int beg = row_ptr[i];
    int cnt = deg[i];
    int k = 0;
    for (; k + 4 <= cnt; k += 4) {
        int2 e0 = csr8[beg + k + 0];
        int2 e1 = csr8[beg + k + 1];
        int2 e2 = csr8[beg + k + 2];
        int2 e3 = csr8[beg + k + 3];
        float n0 = di * __int_as_float(e0.y), n1 = di * __int_as_float(e1.y);
        float n2 = di * __int_as_float(e2.y), n3 = di * __int_as_float(e3.y);
        unsigned u0 = ((const unsigned*)(h + (size_t)e0.x * 128))[lane];
        unsigned u1 = ((const unsigned*)(h + (size_t)e1.x * 128))[lane];
        unsigned u2 = ((const unsigned*)(h + (size_t)e2.x * 128))[lane];
        unsigned u3 = ((const unsigned*)(h + (size_t)e3.x * 128))[lane];
        acc.x += bf_lo(u0) * n0 + bf_lo(u1) * n1 + bf_lo(u2) * n2 + bf_lo(u3) * n3;
        acc.y += bf_hi(u0) * n0 + bf_hi(u1) * n1 + bf_hi(u2) * n2 + bf_hi(u3) * n3;
    }
    for (; k < cnt; ++k) {
        int2 e = csr8[beg + k];
        float nrm = di * __int_as_float(e.y);
        unsigned u = ((const unsigned*)(h + (size_t)e.x * 128))[lane];
        acc.x += bf_lo(u) * nrm; acc.y += bf_hi(u) * nrm;
    }
    ((float2*)&agg[(size_t)i * 128])[lane] = acc;
}

// pull aggregation, 64 bf16 feats, fused +b2 -> out (fp32)
__global__ __launch_bounds__(256) void k_pull64(const __hip_bfloat16* __restrict__ h,
                                                const int* __restrict__ row_ptr,
                                                const int* __restrict__ deg,
                                                const int2* __restrict__ csr8,
                                                const float* __restrict__ dinv,
                                                const float* __restrict__ b2,
                                                float* __restrict__ out, int n) {
    int wave = (blockIdx.x * 256 + threadIdx.x) >> 6;
    int lane = threadIdx.x & 63;
    if (wave >= n) return;
    int i = __builtin_amdgcn_readfirstlane(wave);
    float di = dinv[i];
    const unsigned short* hu = (const unsigned short*)h;
    float acc = bf_lo((unsigned)hu[(size_t)i * 64 + lane] << 0) * 0.0f; // placeholder
    {
        unsigned u = hu[(size_t)i * 64 + lane];
        acc = __uint_as_float(u << 16) * di * di;
    }
    int beg = row_ptr[i];
    int cnt = deg[i];
    int k = 0;
    for (; k + 4 <= cnt; k += 4) {
        int2 e0 = csr8[beg + k + 0];
        int2 e1 = csr8[beg + k + 1];
        int2 e2 = csr8[beg + k + 2];
        int2 e3 = csr8[beg + k + 3];
        float n0 = di * __int_as_float(e0.y), n1 = di * __int_as_float(e1.y);
        float n2 = di * __int_as_float(e2.y), n3 = di * __int_as_float(e3.y);
        float v0 = __uint_as_float((unsigned)hu[(size_t)e0.x * 64 + lane] << 16);
        float v1 = __uint_as_float((unsigned)hu[(size_t)e1.x * 64 + lane] << 16);
        float v2 = __uint_as_float((unsigned)hu[(size_t)e2.x * 64 + lane] << 16);
        float v3 = __uint_as_float((unsigned)hu[(size_t)e3.x * 64 + lane] << 16);
        acc += v0 * n0 + v1 * n1 + v2 * n2 + v3 * n3;
    }
    for (; k < cnt; ++k) {
        int2 e = csr8[beg + k];
        float v = __uint_as_float((unsigned)hu[(size_t)e.x * 64 + lane] << 16);
        acc += v * (di * __int_as_float(e.y));
    }
    out[(size_t)i * 64 + lane] = acc + b2[lane];
}

extern "C" void kernel_launch(void* const* d_in, const int* in_sizes, int n_in,
                              void* d_out, int out_size, void* d_ws, size_t ws_size,
                              hipStream_t stream) {
    const float* x  = (const float*)d_in[0];
    const int*   ei = (const int*)d_in[1];
    const float* W1 = (const float*)d_in[2];
    const float* b1 = (const float*)d_in[3];
    const float* W2 = (const float*)d_in[4];
    const float* b2 = (const float*)d_in[5];
    float* out = (float*)d_out;

    const int N = in_sizes[0] / 128;
    const int E = in_sizes[1] / 2;
    const int* src = ei;
    const int* dst = ei + E;

    float* dinv    = (float*)d_ws;                     // N
    int*   deg     = (int*)(dinv + N);                 // N
    int*   row_ptr = deg + N;                          // N
    int*   cursor  = row_ptr + N;                      // N
    int*   bsum    = cursor + N;                       // 1024
    int2*  csr8    = (int2*)(bsum + 1024);             // E int2
    __hip_bfloat16* bufH = (__hip_bfloat16*)(csr8 + E);// N*128 bf16
    float* bufA    = (float*)(bufH + (size_t)N * 128); // N*128 f32

    const int nb = (N + 255) / 256;                    // scan blocks (391)

    // ---- CSR build + normalization ----
    k_zero<<<(N + 255) / 256, 256, 0, stream>>>(deg, N);
    k_deg<<<(E + 255) / 256, 256, 0, stream>>>(dst, deg, E);
    k_scan1<<<nb, 256, 0, stream>>>(deg, row_ptr, bsum, N);
    k_scan2<<<1, 1024, 0, stream>>>(bsum, nb);
    k_scan3<<<(N + 255) / 256, 256, 0, stream>>>(row_ptr, bsum, deg, cursor, dinv, N);
    k_scatter<<<(E + 255) / 256, 256, 0, stream>>>(src, dst, cursor, dinv, csr8, E);

    // ---- layer 1 ----
    k_gemm1<<<(N + 7) / 8, 256, 0, stream>>>(x, W1, bufH, N);
    k_pull128<<<(N + 3) / 4, 256, 0, stream>>>(bufH, row_ptr, deg, csr8, dinv, bufA, N);

    // ---- layer 2 ----
    k_gemm2<<<(N + 15) / 16, 256, 0, stream>>>(bufA, b1, W2, bufH, N);
    k_pull64<<<(N + 3) / 4, 256, 0, stream>>>(bufH, row_ptr, deg, csr8, dinv, b2, out, N);
}

// Round 5
// 422.400 us; speedup vs baseline: 3.2492x; 1.2243x over previous
//
#include <hip/hip_runtime.h>
#include <hip/hip_bf16.h>

// GCN 2-layer forward, fp32 I/O. CSR pull aggregation (bf16 h storage,
// {src,dinv} fused CSR entries) + MFMA bf16 GEMMs.
// Pipeline:
//  1) deg histogram; hierarchical scan -> row_ptr; dinv = rsqrt(deg+1)
//  2) scatter: csr8[pos] = {src, dinv[src]}
//  3) W1,W2 -> bf16 transposed (k_prepW, once per call)
//  4) h1 = x @ W1 -> bf16                          (k_gemm1, MFMA)
//  5) agg1 = D^-1/2 (A+I) D^-1/2 h1 -> fp32        (k_pull128)
//  6) h2 = relu(agg1 + b1) @ W2 -> bf16            (k_gemm2, MFMA)
//  7) out = aggregate(h2) + b2 -> fp32             (k_pull64)

typedef short short8v __attribute__((ext_vector_type(8)));   // 8 bf16 (4 VGPRs)
typedef float f32x4   __attribute__((ext_vector_type(4)));   // MFMA acc

// RNE fp32 -> bf16 (finite inputs)
__device__ __forceinline__ short f2bf(float f) {
    unsigned u = __float_as_uint(f);
    return (short)((u + 0x7fffu + ((u >> 16) & 1u)) >> 16);
}
__device__ __forceinline__ float bfbits(unsigned short s) {
    return __uint_as_float((unsigned)s << 16);
}

__global__ void k_zero(int* __restrict__ p, int n) {
    int i = blockIdx.x * blockDim.x + threadIdx.x;
    if (i < n) p[i] = 0;
}

__global__ void k_deg(const int* __restrict__ dst, int* __restrict__ deg, int E) {
    int e = blockIdx.x * blockDim.x + threadIdx.x;
    if (e < E) atomicAdd(&deg[dst[e]], 1);
}

// per-256-block exclusive scan; block sums to bsum
__global__ __launch_bounds__(256) void k_scan1(const int* __restrict__ deg,
                                               int* __restrict__ row_ptr,
                                               int* __restrict__ bsum, int n) {
    __shared__ int s[256];
    int t = threadIdx.x;
    int i = blockIdx.x * 256 + t;
    int v = (i < n) ? deg[i] : 0;
    s[t] = v;
    __syncthreads();
    for (int off = 1; off < 256; off <<= 1) {
        int add = (t >= off) ? s[t - off] : 0;
        __syncthreads();
        s[t] += add;
        __syncthreads();
    }
    if (i < n) row_ptr[i] = s[t] - v;           // exclusive
    if (t == 255) bsum[blockIdx.x] = s[255];
}

// single-block exclusive scan of block sums (nb <= 1024)
__global__ __launch_bounds__(1024) void k_scan2(int* __restrict__ bsum, int nb) {
    __shared__ int s[1024];
    int t = threadIdx.x;
    int v = (t < nb) ? bsum[t] : 0;
    s[t] = v;
    __syncthreads();
    for (int off = 1; off < 1024; off <<= 1) {
        int add = (t >= off) ? s[t - off] : 0;
        __syncthreads();
        s[t] += add;
        __syncthreads();
    }
    if (t < nb) bsum[t] = s[t] - v;             // exclusive
}

// add block offsets; init cursor; dinv = rsqrt(deg+1)
__global__ void k_scan3(int* __restrict__ row_ptr, const int* __restrict__ bsum,
                        const int* __restrict__ deg, int* __restrict__ cursor,
                        float* __restrict__ dinv, int n) {
    int i = blockIdx.x * blockDim.x + threadIdx.x;
    if (i >= n) return;
    int rp = row_ptr[i] + bsum[i >> 8];
    row_ptr[i] = rp;
    cursor[i]  = rp;
    dinv[i] = rsqrtf((float)(deg[i] + 1));
}

// csr8[pos] = {src, dinv[src]} — random-write-line bound
__global__ void k_scatter(const int* __restrict__ src, const int* __restrict__ dst,
                          int* __restrict__ cursor, const float* __restrict__ dinv,
                          int2* __restrict__ csr8, int E) {
    int e = blockIdx.x * blockDim.x + threadIdx.x;
    if (e < E) {
        int s = src[e];
        int pos = atomicAdd(&cursor[dst[e]], 1);
        csr8[pos] = make_int2(s, __float_as_int(dinv[s]));
    }
}

// W1[128k][128n] -> w1t[n][k] bf16 ; W2[128k][64n] -> w2t[n][k] bf16
__global__ void k_prepW(const float* __restrict__ W1, const float* __restrict__ W2,
                        short* __restrict__ w1t, short* __restrict__ w2t) {
    int i = blockIdx.x * blockDim.x + threadIdx.x;
    if (i < 128 * 128) {
        int n = i >> 7, k = i & 127;
        w1t[i] = f2bf(W1[k * 128 + n]);
    } else if (i < 128 * 128 + 64 * 128) {
        int j = i - 128 * 128;
        int n = j >> 7, k = j & 127;
        w2t[j] = f2bf(W2[k * 64 + n]);
    }
}

// ---- MFMA GEMM1: h[64rows/block,128] = bf16(x) @ bf16(W1), 256 thr ----
// LDS rows padded +8 shorts (16B) so A/B quad reads are 2-way (free, m136).
#define LDP 136
__global__ __launch_bounds__(256) void k_gemm1(const float* __restrict__ x,
                                               const short* __restrict__ w1t,
                                               short* __restrict__ h, int nrows) {
    __shared__ short xs[64 * LDP];    // 17.4 KB
    __shared__ short wt[128 * LDP];   // 34.8 KB
    int t = threadIdx.x;
    int row0 = blockIdx.x * 64;
    // stage x (fp32 -> bf16), float4 reads, short4 LDS writes
    for (int i = 0; i < 16; ++i) {
        int idx = t + i * 256;               // 4096 float4 total
        int r = idx >> 5, c4 = idx & 31;
        float4 v = make_float4(0.f, 0.f, 0.f, 0.f);
        if (row0 + r < nrows) v = ((const float4*)x)[(size_t)(row0 + r) * 32 + c4];
        short4 o = make_short4(f2bf(v.x), f2bf(v.y), f2bf(v.z), f2bf(v.w));
        *(short4*)&xs[r * LDP + c4 * 4] = o;
    }
    // stage w1t (bf16, [n][k] 128x128), short4 copies
    for (int i = 0; i < 16; ++i) {
        int idx = t + i * 256;               // 4096 short4 total
        int n = idx >> 5, c4 = idx & 31;
        *(short4*)&wt[n * LDP + c4 * 4] = ((const short4*)w1t)[idx];
    }
    __syncthreads();
    int wave = t >> 6, lane = t & 63;
    int quad = lane >> 4, c = lane & 15;
    int m0 = wave * 16;                      // wave's row block
    f32x4 acc[8] = {};
    #pragma unroll
    for (int kc = 0; kc < 4; ++kc) {
        short8v a = *(const short8v*)&xs[(m0 + c) * LDP + kc * 32 + quad * 8];
        #pragma unroll
        for (int nt = 0; nt < 8; ++nt) {
            short8v b = *(const short8v*)&wt[(nt * 16 + c) * LDP + kc * 32 + quad * 8];
            acc[nt] = __builtin_amdgcn_mfma_f32_16x16x32_bf16(a, b, acc[nt], 0, 0, 0);
        }
    }
    // C/D: col = lane&15, row = quad*4 + r   [m89/m91 verified]
    #pragma unroll
    for (int nt = 0; nt < 8; ++nt)
        #pragma unroll
        for (int r = 0; r < 4; ++r) {
            int row = row0 + m0 + quad * 4 + r;
            if (row < nrows) h[(size_t)row * 128 + nt * 16 + c] = f2bf(acc[nt][r]);
        }
}

// ---- MFMA GEMM2: h2[64rows,64] = bf16(relu(agg+b1)) @ bf16(W2) ----
__global__ __launch_bounds__(256) void k_gemm2(const float* __restrict__ a,
                                               const float* __restrict__ b1,
                                               const short* __restrict__ w2t,
                                               short* __restrict__ h2, int nrows) {
    __shared__ short xs[64 * LDP];    // 17.4 KB
    __shared__ short wt[64 * LDP];    // 17.4 KB
    int t = threadIdx.x;
    int row0 = blockIdx.x * 64;
    for (int i = 0; i < 16; ++i) {
        int idx = t + i * 256;
        int r = idx >> 5, c4 = idx & 31;
        float4 v = make_float4(0.f, 0.f, 0.f, 0.f);
        if (row0 + r < nrows) {
            v = ((const float4*)a)[(size_t)(row0 + r) * 32 + c4];
            v.x = fmaxf(v.x + b1[c4 * 4 + 0], 0.f);
            v.y = fmaxf(v.y + b1[c4 * 4 + 1], 0.f);
            v.z = fmaxf(v.z + b1[c4 * 4 + 2], 0.f);
            v.w = fmaxf(v.w + b1[c4 * 4 + 3], 0.f);
        }
        short4 o = make_short4(f2bf(v.x), f2bf(v.y), f2bf(v.z), f2bf(v.w));
        *(short4*)&xs[r * LDP + c4 * 4] = o;
    }
    for (int i = 0; i < 8; ++i) {
        int idx = t + i * 256;               // 2048 short4 total
        int n = idx >> 5, c4 = idx & 31;
        *(short4*)&wt[n * LDP + c4 * 4] = ((const short4*)w2t)[idx];
    }
    __syncthreads();
    int wave = t >> 6, lane = t & 63;
    int quad = lane >> 4, c = lane & 15;
    int m0 = wave * 16;
    f32x4 acc[4] = {};
    #pragma unroll
    for (int kc = 0; kc < 4; ++kc) {
        short8v av = *(const short8v*)&xs[(m0 + c) * LDP + kc * 32 + quad * 8];
        #pragma unroll
        for (int nt = 0; nt < 4; ++nt) {
            short8v b = *(const short8v*)&wt[(nt * 16 + c) * LDP + kc * 32 + quad * 8];
            acc[nt] = __builtin_amdgcn_mfma_f32_16x16x32_bf16(av, b, acc[nt], 0, 0, 0);
        }
    }
    #pragma unroll
    for (int nt = 0; nt < 4; ++nt)
        #pragma unroll
        for (int r = 0; r < 4; ++r) {
            int row = row0 + m0 + quad * 4 + r;
            if (row < nrows) h2[(size_t)row * 64 + nt * 16 + c] = f2bf(acc[nt][r]);
        }
}

// pull aggregation, 128 bf16 feats: one wave/node, lane owns feats [2l,2l+1].
__global__ __launch_bounds__(256) void k_pull128(const unsigned short* __restrict__ h,
                                                 const int* __restrict__ row_ptr,
                                                 const int* __restrict__ deg,
                                                 const int2* __restrict__ csr8,
                                                 const float* __restrict__ dinv,
                                                 float* __restrict__ agg, int n) {
    int wave = (blockIdx.x * 256 + threadIdx.x) >> 6;
    int lane = threadIdx.x & 63;
    if (wave >= n) return;
    int i = __builtin_amdgcn_readfirstlane(wave);
    float di = dinv[i];
    float2 acc;
    {
        unsigned u = ((const unsigned*)(h + (size_t)i * 128))[lane];
        float w = di * di;
        acc.x = __uint_as_float(u << 16) * w;
        acc.y = __uint_as_float(u & 0xffff0000u) * w;
    }
    int beg = row_ptr[i];
    int cnt = deg[i];
    int k = 0;
    for (; k + 4 <= cnt; k += 4) {
        int2 e0 = csr8[beg + k + 0];
        int2 e1 = csr8[beg + k + 1];
        int2 e2 = csr8[beg + k + 2];
        int2 e3 = csr8[beg + k + 3];
        float n0 = di * __int_as_float(e0.y), n1 = di * __int_as_float(e1.y);
        float n2 = di * __int_as_float(e2.y), n3 = di * __int_as_float(e3.y);
        unsigned u0 = ((const unsigned*)(h + (size_t)e0.x * 128))[lane];
        unsigned u1 = ((const unsigned*)(h + (size_t)e1.x * 128))[lane];
        unsigned u2 = ((const unsigned*)(h + (size_t)e2.x * 128))[lane];
        unsigned u3 = ((const unsigned*)(h + (size_t)e3.x * 128))[lane];
        acc.x += __uint_as_float(u0 << 16) * n0 + __uint_as_float(u1 << 16) * n1
               + __uint_as_float(u2 << 16) * n2 + __uint_as_float(u3 << 16) * n3;
        acc.y += __uint_as_float(u0 & 0xffff0000u) * n0 + __uint_as_float(u1 & 0xffff0000u) * n1
               + __uint_as_float(u2 & 0xffff0000u) * n2 + __uint_as_float(u3 & 0xffff0000u) * n3;
    }
    for (; k < cnt; ++k) {
        int2 e = csr8[beg + k];
        float nrm = di * __int_as_float(e.y);
        unsigned u = ((const unsigned*)(h + (size_t)e.x * 128))[lane];
        acc.x += __uint_as_float(u << 16) * nrm;
        acc.y += __uint_as_float(u & 0xffff0000u) * nrm;
    }
    ((float2*)&agg[(size_t)i * 128])[lane] = acc;
}

// pull aggregation, 64 bf16 feats, fused +b2 -> out (fp32)
__global__ __launch_bounds__(256) void k_pull64(const unsigned short* __restrict__ h,
                                                const int* __restrict__ row_ptr,
                                                const int* __restrict__ deg,
                                                const int2* __restrict__ csr8,
                                                const float* __restrict__ dinv,
                                                const float* __restrict__ b2,
                                                float* __restrict__ out, int n) {
    int wave = (blockIdx.x * 256 + threadIdx.x) >> 6;
    int lane = threadIdx.x & 63;
    if (wave >= n) return;
    int i = __builtin_amdgcn_readfirstlane(wave);
    float di = dinv[i];
    float acc = bfbits(h[(size_t)i * 64 + lane]) * di * di;
    int beg = row_ptr[i];
    int cnt = deg[i];
    int k = 0;
    for (; k + 4 <= cnt; k += 4) {
        int2 e0 = csr8[beg + k + 0];
        int2 e1 = csr8[beg + k + 1];
        int2 e2 = csr8[beg + k + 2];
        int2 e3 = csr8[beg + k + 3];
        float n0 = di * __int_as_float(e0.y), n1 = di * __int_as_float(e1.y);
        float n2 = di * __int_as_float(e2.y), n3 = di * __int_as_float(e3.y);
        acc += bfbits(h[(size_t)e0.x * 64 + lane]) * n0
             + bfbits(h[(size_t)e1.x * 64 + lane]) * n1
             + bfbits(h[(size_t)e2.x * 64 + lane]) * n2
             + bfbits(h[(size_t)e3.x * 64 + lane]) * n3;
    }
    for (; k < cnt; ++k) {
        int2 e = csr8[beg + k];
        acc += bfbits(h[(size_t)e.x * 64 + lane]) * (di * __int_as_float(e.y));
    }
    out[(size_t)i * 64 + lane] = acc + b2[lane];
}

extern "C" void kernel_launch(void* const* d_in, const int* in_sizes, int n_in,
                              void* d_out, int out_size, void* d_ws, size_t ws_size,
                              hipStream_t stream) {
    const float* x  = (const float*)d_in[0];
    const int*   ei = (const int*)d_in[1];
    const float* W1 = (const float*)d_in[2];
    const float* b1 = (const float*)d_in[3];
    const float* W2 = (const float*)d_in[4];
    const float* b2 = (const float*)d_in[5];
    float* out = (float*)d_out;

    const int N = in_sizes[0] / 128;
    const int E = in_sizes[1] / 2;
    const int* src = ei;
    const int* dst = ei + E;

    float* dinv    = (float*)d_ws;                     // N
    int*   deg     = (int*)(dinv + N);                 // N
    int*   row_ptr = deg + N;                          // N
    int*   cursor  = row_ptr + N;                      // N
    int*   bsum    = cursor + N;                       // 1024
    short* w1t     = (short*)(bsum + 1024);            // 128*128
    short* w2t     = w1t + 128 * 128;                  // 64*128
    int2*  csr8    = (int2*)(w2t + 64 * 128);          // E int2
    short* bufH    = (short*)(csr8 + E);               // N*128 bf16
    float* bufA    = (float*)(bufH + (size_t)N * 128); // N*128 f32

    const int nb = (N + 255) / 256;                    // scan blocks (391)

    // ---- CSR build + normalization + weight prep ----
    k_zero<<<(N + 255) / 256, 256, 0, stream>>>(deg, N);
    k_deg<<<(E + 255) / 256, 256, 0, stream>>>(dst, deg, E);
    k_scan1<<<nb, 256, 0, stream>>>(deg, row_ptr, bsum, N);
    k_scan2<<<1, 1024, 0, stream>>>(bsum, nb);
    k_scan3<<<(N + 255) / 256, 256, 0, stream>>>(row_ptr, bsum, deg, cursor, dinv, N);
    k_scatter<<<(E + 255) / 256, 256, 0, stream>>>(src, dst, cursor, dinv, csr8, E);
    k_prepW<<<96, 256, 0, stream>>>(W1, W2, w1t, w2t);

    // ---- layer 1 ----
    k_gemm1<<<(N + 63) / 64, 256, 0, stream>>>(x, w1t, bufH, N);
    k_pull128<<<(N + 3) / 4, 256, 0, stream>>>((const unsigned short*)bufH, row_ptr, deg, csr8, dinv, bufA, N);

    // ---- layer 2 ----
    k_gemm2<<<(N + 63) / 64, 256, 0, stream>>>(bufA, b1, w2t, bufH, N);
    k_pull64<<<(N + 3) / 4, 256, 0, stream>>>((const unsigned short*)bufH, row_ptr, deg, csr8, dinv, b2, out, N);
}

// Round 6
// 418.844 us; speedup vs baseline: 3.2768x; 1.0085x over previous
//
#include <hip/hip_runtime.h>
#include <hip/hip_bf16.h>

// GCN 2-layer forward, fp32 I/O. CSR pull aggregation (bf16 h storage,
// {src,dinv} fused CSR entries) + MFMA bf16 GEMMs + two-phase bucketed
// CSR build (dense-in-time writes -> L2 write combining).
// Pipeline:
//  1) deg histogram; hierarchical scan -> row_ptr/cursor; dinv = rsqrt(deg+1)
//  2) bucket hist/scan; phase A partition {src,dst} by dst>>9 into ebuf
//  3) phase B: scatter ebuf -> csr8 = {src, dinv[src]} (writes L2-localized)
//  4) h1 = x @ W1 -> bf16                          (k_gemm1, MFMA)
//  5) agg1 = D^-1/2 (A+I) D^-1/2 h1 -> fp32        (k_pull128)
//  6) h2 = relu(agg1 + b1) @ W2 -> bf16            (k_gemm2, MFMA)
//  7) out = aggregate(h2) + b2 -> fp32             (k_pull64)

typedef short short8v __attribute__((ext_vector_type(8)));   // 8 bf16 (4 VGPRs)
typedef float f32x4   __attribute__((ext_vector_type(4)));   // MFMA acc

#define BSHIFT 9          // bucket = dst >> 9  (span 512 nodes)

// RNE fp32 -> bf16 (finite inputs)
__device__ __forceinline__ short f2bf(float f) {
    unsigned u = __float_as_uint(f);
    return (short)((u + 0x7fffu + ((u >> 16) & 1u)) >> 16);
}
__device__ __forceinline__ float bfbits(unsigned short s) {
    return __uint_as_float((unsigned)s << 16);
}

__global__ void k_zero(int* __restrict__ p, int n) {
    int i = blockIdx.x * blockDim.x + threadIdx.x;
    if (i < n) p[i] = 0;
}

__global__ void k_deg(const int* __restrict__ dst, int* __restrict__ deg, int E) {
    int e = blockIdx.x * blockDim.x + threadIdx.x;
    if (e < E) atomicAdd(&deg[dst[e]], 1);
}

// per-256-block exclusive scan; block sums to bsum
__global__ __launch_bounds__(256) void k_scan1(const int* __restrict__ deg,
                                               int* __restrict__ row_ptr,
                                               int* __restrict__ bsum, int n) {
    __shared__ int s[256];
    int t = threadIdx.x;
    int i = blockIdx.x * 256 + t;
    int v = (i < n) ? deg[i] : 0;
    s[t] = v;
    __syncthreads();
    for (int off = 1; off < 256; off <<= 1) {
        int add = (t >= off) ? s[t - off] : 0;
        __syncthreads();
        s[t] += add;
        __syncthreads();
    }
    if (i < n) row_ptr[i] = s[t] - v;           // exclusive
    if (t == 255) bsum[blockIdx.x] = s[255];
}

// single-block exclusive scan of block sums (nb <= 1024)
__global__ __launch_bounds__(1024) void k_scan2(int* __restrict__ bsum, int nb) {
    __shared__ int s[1024];
    int t = threadIdx.x;
    int v = (t < nb) ? bsum[t] : 0;
    s[t] = v;
    __syncthreads();
    for (int off = 1; off < 1024; off <<= 1) {
        int add = (t >= off) ? s[t - off] : 0;
        __syncthreads();
        s[t] += add;
        __syncthreads();
    }
    if (t < nb) bsum[t] = s[t] - v;             // exclusive
}

// add block offsets; init cursor; dinv = rsqrt(deg+1)
__global__ void k_scan3(int* __restrict__ row_ptr, const int* __restrict__ bsum,
                        const int* __restrict__ deg, int* __restrict__ cursor,
                        float* __restrict__ dinv, int n) {
    int i = blockIdx.x * blockDim.x + threadIdx.x;
    if (i >= n) return;
    int rp = row_ptr[i] + bsum[i >> 8];
    row_ptr[i] = rp;
    cursor[i]  = rp;
    dinv[i] = rsqrtf((float)(deg[i] + 1));
}

// ---- bucket histogram over dst>>BSHIFT (LDS-aggregated) ----
__global__ __launch_bounds__(256) void k_bhist(const int* __restrict__ dst,
                                               int* __restrict__ bcnt, int E, int nbuck) {
    __shared__ int hist[256];
    int t = threadIdx.x;
    for (int i = t; i < nbuck; i += 256) hist[i] = 0;
    __syncthreads();
    int e0 = blockIdx.x * 4096;
    for (int i = 0; i < 16; ++i) {
        int e = e0 + i * 256 + t;
        if (e < E) atomicAdd(&hist[dst[e] >> BSHIFT], 1);
    }
    __syncthreads();
    for (int i = t; i < nbuck; i += 256)
        if (hist[i]) atomicAdd(&bcnt[i], hist[i]);
}

// single-block exclusive scan of bucket counts -> bucket cursors (nbuck<=256)
__global__ __launch_bounds__(256) void k_bscan(const int* __restrict__ bcnt,
                                               int* __restrict__ bcur, int nbuck) {
    __shared__ int s[256];
    int t = threadIdx.x;
    int v = (t < nbuck) ? bcnt[t] : 0;
    s[t] = v;
    __syncthreads();
    for (int off = 1; off < 256; off <<= 1) {
        int add = (t >= off) ? s[t - off] : 0;
        __syncthreads();
        s[t] += add;
        __syncthreads();
    }
    if (t < nbuck) bcur[t] = s[t] - v;
}

// ---- phase A: partition edges by bucket into ebuf (grouped chunk writes) ----
__global__ __launch_bounds__(256) void k_bucket(const int* __restrict__ src,
                                                const int* __restrict__ dst,
                                                int* __restrict__ bcur,
                                                int2* __restrict__ ebuf,
                                                int E, int nbuck) {
    __shared__ int hist[256];
    __shared__ int base[256];
    int t = threadIdx.x;
    int e0 = blockIdx.x * 4096;
    for (int i = t; i < nbuck; i += 256) hist[i] = 0;
    __syncthreads();
    for (int i = 0; i < 16; ++i) {                    // pass 1: local histogram
        int e = e0 + i * 256 + t;
        if (e < E) atomicAdd(&hist[dst[e] >> BSHIFT], 1);
    }
    __syncthreads();
    for (int b = t; b < nbuck; b += 256) {            // pass 2: reserve chunks
        int c = hist[b];
        base[b] = c ? atomicAdd(&bcur[b], c) : 0;
        hist[b] = 0;
    }
    __syncthreads();
    for (int i = 0; i < 16; ++i) {                    // pass 3: grouped writes
        int e = e0 + i * 256 + t;
        if (e < E) {
            int d = dst[e];
            int bk = d >> BSHIFT;
            int off = atomicAdd(&hist[bk], 1);
            ebuf[base[bk] + off] = make_int2(src[e], d);
        }
    }
}

// ---- phase B: bucketed edges -> csr8; writes localized to ~65KB segments ----
__global__ void k_scatter2(const int2* __restrict__ ebuf, int* __restrict__ cursor,
                           const float* __restrict__ dinv, int2* __restrict__ csr8,
                           int E) {
    int e = blockIdx.x * blockDim.x + threadIdx.x;
    if (e < E) {
        int2 ed = ebuf[e];
        int pos = atomicAdd(&cursor[ed.y], 1);
        csr8[pos] = make_int2(ed.x, __float_as_int(dinv[ed.x]));
    }
}

// W1[128k][128n] -> w1t[n][k] bf16 ; W2[128k][64n] -> w2t[n][k] bf16
__global__ void k_prepW(const float* __restrict__ W1, const float* __restrict__ W2,
                        short* __restrict__ w1t, short* __restrict__ w2t) {
    int i = blockIdx.x * blockDim.x + threadIdx.x;
    if (i < 128 * 128) {
        int n = i >> 7, k = i & 127;
        w1t[i] = f2bf(W1[k * 128 + n]);
    } else if (i < 128 * 128 + 64 * 128) {
        int j = i - 128 * 128;
        int n = j >> 7, k = j & 127;
        w2t[j] = f2bf(W2[k * 64 + n]);
    }
}

// ---- MFMA GEMM1: h[64rows/block,128] = bf16(x) @ bf16(W1), 256 thr ----
#define LDP 136
__global__ __launch_bounds__(256) void k_gemm1(const float* __restrict__ x,
                                               const short* __restrict__ w1t,
                                               short* __restrict__ h, int nrows) {
    __shared__ short xs[64 * LDP];
    __shared__ short wt[128 * LDP];
    int t = threadIdx.x;
    int row0 = blockIdx.x * 64;
    for (int i = 0; i < 16; ++i) {
        int idx = t + i * 256;
        int r = idx >> 5, c4 = idx & 31;
        float4 v = make_float4(0.f, 0.f, 0.f, 0.f);
        if (row0 + r < nrows) v = ((const float4*)x)[(size_t)(row0 + r) * 32 + c4];
        short4 o = make_short4(f2bf(v.x), f2bf(v.y), f2bf(v.z), f2bf(v.w));
        *(short4*)&xs[r * LDP + c4 * 4] = o;
    }
    for (int i = 0; i < 16; ++i) {
        int idx = t + i * 256;
        int n = idx >> 5, c4 = idx & 31;
        *(short4*)&wt[n * LDP + c4 * 4] = ((const short4*)w1t)[idx];
    }
    __syncthreads();
    int wave = t >> 6, lane = t & 63;
    int quad = lane >> 4, c = lane & 15;
    int m0 = wave * 16;
    f32x4 acc[8] = {};
    #pragma unroll
    for (int kc = 0; kc < 4; ++kc) {
        short8v a = *(const short8v*)&xs[(m0 + c) * LDP + kc * 32 + quad * 8];
        #pragma unroll
        for (int nt = 0; nt < 8; ++nt) {
            short8v b = *(const short8v*)&wt[(nt * 16 + c) * LDP + kc * 32 + quad * 8];
            acc[nt] = __builtin_amdgcn_mfma_f32_16x16x32_bf16(a, b, acc[nt], 0, 0, 0);
        }
    }
    #pragma unroll
    for (int nt = 0; nt < 8; ++nt)
        #pragma unroll
        for (int r = 0; r < 4; ++r) {
            int row = row0 + m0 + quad * 4 + r;
            if (row < nrows) h[(size_t)row * 128 + nt * 16 + c] = f2bf(acc[nt][r]);
        }
}

// ---- MFMA GEMM2: h2[64rows,64] = bf16(relu(agg+b1)) @ bf16(W2) ----
__global__ __launch_bounds__(256) void k_gemm2(const float* __restrict__ a,
                                               const float* __restrict__ b1,
                                               const short* __restrict__ w2t,
                                               short* __restrict__ h2, int nrows) {
    __shared__ short xs[64 * LDP];
    __shared__ short wt[64 * LDP];
    int t = threadIdx.x;
    int row0 = blockIdx.x * 64;
    for (int i = 0; i < 16; ++i) {
        int idx = t + i * 256;
        int r = idx >> 5, c4 = idx & 31;
        float4 v = make_float4(0.f, 0.f, 0.f, 0.f);
        if (row0 + r < nrows) {
            v = ((const float4*)a)[(size_t)(row0 + r) * 32 + c4];
            v.x = fmaxf(v.x + b1[c4 * 4 + 0], 0.f);
            v.y = fmaxf(v.y + b1[c4 * 4 + 1], 0.f);
            v.z = fmaxf(v.z + b1[c4 * 4 + 2], 0.f);
            v.w = fmaxf(v.w + b1[c4 * 4 + 3], 0.f);
        }
        short4 o = make_short4(f2bf(v.x), f2bf(v.y), f2bf(v.z), f2bf(v.w));
        *(short4*)&xs[r * LDP + c4 * 4] = o;
    }
    for (int i = 0; i < 8; ++i) {
        int idx = t + i * 256;
        int n = idx >> 5, c4 = idx & 31;
        *(short4*)&wt[n * LDP + c4 * 4] = ((const short4*)w2t)[idx];
    }
    __syncthreads();
    int wave = t >> 6, lane = t & 63;
    int quad = lane >> 4, c = lane & 15;
    int m0 = wave * 16;
    f32x4 acc[4] = {};
    #pragma unroll
    for (int kc = 0; kc < 4; ++kc) {
        short8v av = *(const short8v*)&xs[(m0 + c) * LDP + kc * 32 + quad * 8];
        #pragma unroll
        for (int nt = 0; nt < 4; ++nt) {
            short8v b = *(const short8v*)&wt[(nt * 16 + c) * LDP + kc * 32 + quad * 8];
            acc[nt] = __builtin_amdgcn_mfma_f32_16x16x32_bf16(av, b, acc[nt], 0, 0, 0);
        }
    }
    #pragma unroll
    for (int nt = 0; nt < 4; ++nt)
        #pragma unroll
        for (int r = 0; r < 4; ++r) {
            int row = row0 + m0 + quad * 4 + r;
            if (row < nrows) h2[(size_t)row * 64 + nt * 16 + c] = f2bf(acc[nt][r]);
        }
}

// pull aggregation, 128 bf16 feats: one wave/node, lane owns feats [2l,2l+1].
__global__ __launch_bounds__(256) void k_pull128(const unsigned short* __restrict__ h,
                                                 const int* __restrict__ row_ptr,
                                                 const int* __restrict__ deg,
                                                 const int2* __restrict__ csr8,
                                                 const float* __restrict__ dinv,
                                                 float* __restrict__ agg, int n) {
    int wave = (blockIdx.x * 256 + threadIdx.x) >> 6;
    int lane = threadIdx.x & 63;
    if (wave >= n) return;
    int i = __builtin_amdgcn_readfirstlane(wave);
    float di = dinv[i];
    float2 acc;
    {
        unsigned u = ((const unsigned*)(h + (size_t)i * 128))[lane];
        float w = di * di;
        acc.x = __uint_as_float(u << 16) * w;
        acc.y = __uint_as_float(u & 0xffff0000u) * w;
    }
    int beg = row_ptr[i];
    int cnt = deg[i];
    int k = 0;
    for (; k + 4 <= cnt; k += 4) {
        int2 e0 = csr8[beg + k + 0];
        int2 e1 = csr8[beg + k + 1];
        int2 e2 = csr8[beg + k + 2];
        int2 e3 = csr8[beg + k + 3];
        float n0 = di * __int_as_float(e0.y), n1 = di * __int_as_float(e1.y);
        float n2 = di * __int_as_float(e2.y), n3 = di * __int_as_float(e3.y);
        unsigned u0 = ((const unsigned*)(h + (size_t)e0.x * 128))[lane];
        unsigned u1 = ((const unsigned*)(h + (size_t)e1.x * 128))[lane];
        unsigned u2 = ((const unsigned*)(h + (size_t)e2.x * 128))[lane];
        unsigned u3 = ((const unsigned*)(h + (size_t)e3.x * 128))[lane];
        acc.x += __uint_as_float(u0 << 16) * n0 + __uint_as_float(u1 << 16) * n1
               + __uint_as_float(u2 << 16) * n2 + __uint_as_float(u3 << 16) * n3;
        acc.y += __uint_as_float(u0 & 0xffff0000u) * n0 + __uint_as_float(u1 & 0xffff0000u) * n1
               + __uint_as_float(u2 & 0xffff0000u) * n2 + __uint_as_float(u3 & 0xffff0000u) * n3;
    }
    for (; k < cnt; ++k) {
        int2 e = csr8[beg + k];
        float nrm = di * __int_as_float(e.y);
        unsigned u = ((const unsigned*)(h + (size_t)e.x * 128))[lane];
        acc.x += __uint_as_float(u << 16) * nrm;
        acc.y += __uint_as_float(u & 0xffff0000u) * nrm;
    }
    ((float2*)&agg[(size_t)i * 128])[lane] = acc;
}

// pull aggregation, 64 bf16 feats, fused +b2 -> out (fp32)
__global__ __launch_bounds__(256) void k_pull64(const unsigned short* __restrict__ h,
                                                const int* __restrict__ row_ptr,
                                                const int* __restrict__ deg,
                                                const int2* __restrict__ csr8,
                                                const float* __restrict__ dinv,
                                                const float* __restrict__ b2,
                                                float* __restrict__ out, int n) {
    int wave = (blockIdx.x * 256 + threadIdx.x) >> 6;
    int lane = threadIdx.x & 63;
    if (wave >= n) return;
    int i = __builtin_amdgcn_readfirstlane(wave);
    float di = dinv[i];
    float acc = bfbits(h[(size_t)i * 64 + lane]) * di * di;
    int beg = row_ptr[i];
    int cnt = deg[i];
    int k = 0;
    for (; k + 4 <= cnt; k += 4) {
        int2 e0 = csr8[beg + k + 0];
        int2 e1 = csr8[beg + k + 1];
        int2 e2 = csr8[beg + k + 2];
        int2 e3 = csr8[beg + k + 3];
        float n0 = di * __int_as_float(e0.y), n1 = di * __int_as_float(e1.y);
        float n2 = di * __int_as_float(e2.y), n3 = di * __int_as_float(e3.y);
        acc += bfbits(h[(size_t)e0.x * 64 + lane]) * n0
             + bfbits(h[(size_t)e1.x * 64 + lane]) * n1
             + bfbits(h[(size_t)e2.x * 64 + lane]) * n2
             + bfbits(h[(size_t)e3.x * 64 + lane]) * n3;
    }
    for (; k < cnt; ++k) {
        int2 e = csr8[beg + k];
        acc += bfbits(h[(size_t)e.x * 64 + lane]) * (di * __int_as_float(e.y));
    }
    out[(size_t)i * 64 + lane] = acc + b2[lane];
}

extern "C" void kernel_launch(void* const* d_in, const int* in_sizes, int n_in,
                              void* d_out, int out_size, void* d_ws, size_t ws_size,
                              hipStream_t stream) {
    const float* x  = (const float*)d_in[0];
    const int*   ei = (const int*)d_in[1];
    const float* W1 = (const float*)d_in[2];
    const float* b1 = (const float*)d_in[3];
    const float* W2 = (const float*)d_in[4];
    const float* b2 = (const float*)d_in[5];
    float* out = (float*)d_out;

    const int N = in_sizes[0] / 128;
    const int E = in_sizes[1] / 2;
    const int* src = ei;
    const int* dst = ei + E;
    const int nbuck = (N + (1 << BSHIFT) - 1) >> BSHIFT;   // 196 for N=100000

    float* dinv    = (float*)d_ws;                     // N
    int*   deg     = (int*)(dinv + N);                 // N
    int*   row_ptr = deg + N;                          // N
    int*   cursor  = row_ptr + N;                      // N
    int*   bsum    = cursor + N;                       // 1024
    int*   bcnt    = bsum + 1024;                      // 256
    int*   bcur    = bcnt + 256;                       // 256
    short* w1t     = (short*)(bcur + 256);             // 128*128
    short* w2t     = w1t + 128 * 128;                  // 64*128
    int2*  csr8    = (int2*)(w2t + 64 * 128);          // E int2
    short* bufH    = (short*)(csr8 + E);               // N*128 bf16
    float* bufA    = (float*)(bufH + (size_t)N * 128); // N*128 f32
    int2*  ebuf    = (int2*)bufA;                      // E int2 (aliases bufA;
                                                       // CSR build finishes
                                                       // before bufA is used)

    const int nb = (N + 255) / 256;                    // scan blocks (391)
    const int ntile = (E + 4095) / 4096;               // bucket tiles

    // ---- per-node degree/row_ptr/dinv ----
    k_zero<<<(N + 255) / 256, 256, 0, stream>>>(deg, N);
    k_deg<<<(E + 255) / 256, 256, 0, stream>>>(dst, deg, E);
    k_scan1<<<nb, 256, 0, stream>>>(deg, row_ptr, bsum, N);
    k_scan2<<<1, 1024, 0, stream>>>(bsum, nb);
    k_scan3<<<(N + 255) / 256, 256, 0, stream>>>(row_ptr, bsum, deg, cursor, dinv, N);

    // ---- two-phase bucketed CSR build ----
    k_zero<<<1, 256, 0, stream>>>(bcnt, nbuck);
    k_bhist<<<ntile, 256, 0, stream>>>(dst, bcnt, E, nbuck);
    k_bscan<<<1, 256, 0, stream>>>(bcnt, bcur, nbuck);
    k_bucket<<<ntile, 256, 0, stream>>>(src, dst, bcur, ebuf, E, nbuck);
    k_scatter2<<<(E + 255) / 256, 256, 0, stream>>>(ebuf, cursor, dinv, csr8, E);

    k_prepW<<<96, 256, 0, stream>>>(W1, W2, w1t, w2t);

    // ---- layer 1 ----
    k_gemm1<<<(N + 63) / 64, 256, 0, stream>>>(x, w1t, bufH, N);
    k_pull128<<<(N + 3) / 4, 256, 0, stream>>>((const unsigned short*)bufH, row_ptr, deg, csr8, dinv, bufA, N);

    // ---- layer 2 ----
    k_gemm2<<<(N + 63) / 64, 256, 0, stream>>>(bufA, b1, w2t, bufH, N);
    k_pull64<<<(N + 3) / 4, 256, 0, stream>>>((const unsigned short*)bufH, row_ptr, deg, csr8, dinv, b2, out, N);
}

// Round 7
// 330.641 us; speedup vs baseline: 4.1509x; 1.2668x over previous
//
#include <hip/hip_runtime.h>
#include <hip/hip_bf16.h>

// GCN 2-layer forward, fp32 I/O. Fully-bucketed CSR build (all per-node
// atomics in LDS) + bf16 h storage + {src,dinv} fused CSR + MFMA GEMMs.
// Pipeline:
//  1) k_bhist/k_bscan: bucket (dst>>9) counts -> bases
//  2) k_bucket: partition {src,dst} into ebuf (chunked grouped writes)
//  3) k_bdeg:  per-bucket LDS hist -> deg, dinv, row_ptr (LDS scan + base)
//  4) k_bscatter: per-bucket LDS-cursor scatter -> csr8 = {src, dinv[src]}
//  5) h1 = x @ W1 -> bf16                          (k_gemm1, MFMA)
//  6) agg1 = D^-1/2 (A+I) D^-1/2 h1 -> fp32        (k_pull128)
//  7) h2 = relu(agg1 + b1) @ W2 -> bf16            (k_gemm2, MFMA)
//  8) out = aggregate(h2) + b2 -> fp32             (k_pull64)

typedef short short8v __attribute__((ext_vector_type(8)));   // 8 bf16 (4 VGPRs)
typedef float f32x4   __attribute__((ext_vector_type(4)));   // MFMA acc

#define BSHIFT 9          // bucket = dst >> 9  (span 512 nodes)
#define BSIZE  512

// RNE fp32 -> bf16 (finite inputs)
__device__ __forceinline__ short f2bf(float f) {
    unsigned u = __float_as_uint(f);
    return (short)((u + 0x7fffu + ((u >> 16) & 1u)) >> 16);
}
__device__ __forceinline__ float bfbits(unsigned short s) {
    return __uint_as_float((unsigned)s << 16);
}

__global__ void k_zero(int* __restrict__ p, int n) {
    int i = blockIdx.x * blockDim.x + threadIdx.x;
    if (i < n) p[i] = 0;
}

// ---- bucket histogram over dst>>BSHIFT (LDS-aggregated) ----
__global__ __launch_bounds__(256) void k_bhist(const int* __restrict__ dst,
                                               int* __restrict__ bcnt, int E, int nbuck) {
    __shared__ int hist[256];
    int t = threadIdx.x;
    for (int i = t; i < nbuck; i += 256) hist[i] = 0;
    __syncthreads();
    int e0 = blockIdx.x * 4096;
    for (int i = 0; i < 16; ++i) {
        int e = e0 + i * 256 + t;
        if (e < E) atomicAdd(&hist[dst[e] >> BSHIFT], 1);
    }
    __syncthreads();
    for (int i = t; i < nbuck; i += 256)
        if (hist[i]) atomicAdd(&bcnt[i], hist[i]);
}

// exclusive scan of bucket counts -> bcur (mutable) and bbase (pristine)
__global__ __launch_bounds__(256) void k_bscan(const int* __restrict__ bcnt,
                                               int* __restrict__ bcur,
                                               int* __restrict__ bbase, int nbuck) {
    __shared__ int s[256];
    int t = threadIdx.x;
    int v = (t < nbuck) ? bcnt[t] : 0;
    s[t] = v;
    __syncthreads();
    for (int off = 1; off < 256; off <<= 1) {
        int add = (t >= off) ? s[t - off] : 0;
        __syncthreads();
        s[t] += add;
        __syncthreads();
    }
    if (t < nbuck) { bcur[t] = s[t] - v; bbase[t] = s[t] - v; }
}

// ---- phase A: partition edges by bucket into ebuf (grouped chunk writes) ----
__global__ __launch_bounds__(256) void k_bucket(const int* __restrict__ src,
                                                const int* __restrict__ dst,
                                                int* __restrict__ bcur,
                                                int2* __restrict__ ebuf,
                                                int E, int nbuck) {
    __shared__ int hist[256];
    __shared__ int base[256];
    int t = threadIdx.x;
    int e0 = blockIdx.x * 4096;
    for (int i = t; i < nbuck; i += 256) hist[i] = 0;
    __syncthreads();
    for (int i = 0; i < 16; ++i) {                    // pass 1: local histogram
        int e = e0 + i * 256 + t;
        if (e < E) atomicAdd(&hist[dst[e] >> BSHIFT], 1);
    }
    __syncthreads();
    for (int b = t; b < nbuck; b += 256) {            // pass 2: reserve chunks
        int c = hist[b];
        base[b] = c ? atomicAdd(&bcur[b], c) : 0;
        hist[b] = 0;
    }
    __syncthreads();
    for (int i = 0; i < 16; ++i) {                    // pass 3: grouped writes
        int e = e0 + i * 256 + t;
        if (e < E) {
            int d = dst[e];
            int bk = d >> BSHIFT;
            int off = atomicAdd(&hist[bk], 1);
            ebuf[base[bk] + off] = make_int2(src[e], d);
        }
    }
}

// ---- per-bucket: LDS hist -> deg, dinv; LDS scan + bucket base -> row_ptr ----
__global__ __launch_bounds__(BSIZE) void k_bdeg(const int2* __restrict__ ebuf,
                                                const int* __restrict__ bbase,
                                                const int* __restrict__ bcnt,
                                                int* __restrict__ deg,
                                                int* __restrict__ row_ptr,
                                                float* __restrict__ dinv, int n) {
    __shared__ int hist[BSIZE];
    __shared__ int s[BSIZE];
    int b = blockIdx.x;
    int t = threadIdx.x;
    hist[t] = 0;
    __syncthreads();
    int base = bbase[b], cnt = bcnt[b];
    int lo = b << BSHIFT;
    for (int k = t; k < cnt; k += BSIZE)
        atomicAdd(&hist[ebuf[base + k].y - lo], 1);   // LDS atomic only
    __syncthreads();
    int v = hist[t];
    s[t] = v;
    __syncthreads();
    for (int off = 1; off < BSIZE; off <<= 1) {
        int add = (t >= off) ? s[t - off] : 0;
        __syncthreads();
        s[t] += add;
        __syncthreads();
    }
    int node = lo + t;
    if (node < n) {
        deg[node]     = v;
        row_ptr[node] = base + s[t] - v;              // global CSR offset
        dinv[node]    = rsqrtf((float)(v + 1));
    }
}

// ---- per-bucket: scatter ebuf -> csr8 with LDS cursors ----
__global__ __launch_bounds__(BSIZE) void k_bscatter(const int2* __restrict__ ebuf,
                                                    const int* __restrict__ bbase,
                                                    const int* __restrict__ bcnt,
                                                    const int* __restrict__ row_ptr,
                                                    const float* __restrict__ dinv,
                                                    int2* __restrict__ csr8, int n) {
    __shared__ int cur[BSIZE];
    int b = blockIdx.x;
    int t = threadIdx.x;
    int lo = b << BSHIFT;
    int node = lo + t;
    cur[t] = (node < n) ? row_ptr[node] : 0;
    __syncthreads();
    int base = bbase[b], cnt = bcnt[b];
    for (int k = t; k < cnt; k += BSIZE) {
        int2 ed = ebuf[base + k];
        int pos = atomicAdd(&cur[ed.y - lo], 1);      // LDS atomic only
        csr8[pos] = make_int2(ed.x, __float_as_int(dinv[ed.x]));
    }
}

// W1[128k][128n] -> w1t[n][k] bf16 ; W2[128k][64n] -> w2t[n][k] bf16
__global__ void k_prepW(const float* __restrict__ W1, const float* __restrict__ W2,
                        short* __restrict__ w1t, short* __restrict__ w2t) {
    int i = blockIdx.x * blockDim.x + threadIdx.x;
    if (i < 128 * 128) {
        int n = i >> 7, k = i & 127;
        w1t[i] = f2bf(W1[k * 128 + n]);
    } else if (i < 128 * 128 + 64 * 128) {
        int j = i - 128 * 128;
        int n = j >> 7, k = j & 127;
        w2t[j] = f2bf(W2[k * 64 + n]);
    }
}

// ---- MFMA GEMM1: h[64rows/block,128] = bf16(x) @ bf16(W1), 256 thr ----
#define LDP 136
__global__ __launch_bounds__(256) void k_gemm1(const float* __restrict__ x,
                                               const short* __restrict__ w1t,
                                               short* __restrict__ h, int nrows) {
    __shared__ short xs[64 * LDP];
    __shared__ short wt[128 * LDP];
    int t = threadIdx.x;
    int row0 = blockIdx.x * 64;
    for (int i = 0; i < 16; ++i) {
        int idx = t + i * 256;
        int r = idx >> 5, c4 = idx & 31;
        float4 v = make_float4(0.f, 0.f, 0.f, 0.f);
        if (row0 + r < nrows) v = ((const float4*)x)[(size_t)(row0 + r) * 32 + c4];
        short4 o = make_short4(f2bf(v.x), f2bf(v.y), f2bf(v.z), f2bf(v.w));
        *(short4*)&xs[r * LDP + c4 * 4] = o;
    }
    for (int i = 0; i < 16; ++i) {
        int idx = t + i * 256;
        int n = idx >> 5, c4 = idx & 31;
        *(short4*)&wt[n * LDP + c4 * 4] = ((const short4*)w1t)[idx];
    }
    __syncthreads();
    int wave = t >> 6, lane = t & 63;
    int quad = lane >> 4, c = lane & 15;
    int m0 = wave * 16;
    f32x4 acc[8] = {};
    #pragma unroll
    for (int kc = 0; kc < 4; ++kc) {
        short8v a = *(const short8v*)&xs[(m0 + c) * LDP + kc * 32 + quad * 8];
        #pragma unroll
        for (int nt = 0; nt < 8; ++nt) {
            short8v b = *(const short8v*)&wt[(nt * 16 + c) * LDP + kc * 32 + quad * 8];
            acc[nt] = __builtin_amdgcn_mfma_f32_16x16x32_bf16(a, b, acc[nt], 0, 0, 0);
        }
    }
    #pragma unroll
    for (int nt = 0; nt < 8; ++nt)
        #pragma unroll
        for (int r = 0; r < 4; ++r) {
            int row = row0 + m0 + quad * 4 + r;
            if (row < nrows) h[(size_t)row * 128 + nt * 16 + c] = f2bf(acc[nt][r]);
        }
}

// ---- MFMA GEMM2: h2[64rows,64] = bf16(relu(agg+b1)) @ bf16(W2) ----
__global__ __launch_bounds__(256) void k_gemm2(const float* __restrict__ a,
                                               const float* __restrict__ b1,
                                               const short* __restrict__ w2t,
                                               short* __restrict__ h2, int nrows) {
    __shared__ short xs[64 * LDP];
    __shared__ short wt[64 * LDP];
    int t = threadIdx.x;
    int row0 = blockIdx.x * 64;
    for (int i = 0; i < 16; ++i) {
        int idx = t + i * 256;
        int r = idx >> 5, c4 = idx & 31;
        float4 v = make_float4(0.f, 0.f, 0.f, 0.f);
        if (row0 + r < nrows) {
            v = ((const float4*)a)[(size_t)(row0 + r) * 32 + c4];
            v.x = fmaxf(v.x + b1[c4 * 4 + 0], 0.f);
            v.y = fmaxf(v.y + b1[c4 * 4 + 1], 0.f);
            v.z = fmaxf(v.z + b1[c4 * 4 + 2], 0.f);
            v.w = fmaxf(v.w + b1[c4 * 4 + 3], 0.f);
        }
        short4 o = make_short4(f2bf(v.x), f2bf(v.y), f2bf(v.z), f2bf(v.w));
        *(short4*)&xs[r * LDP + c4 * 4] = o;
    }
    for (int i = 0; i < 8; ++i) {
        int idx = t + i * 256;
        int n = idx >> 5, c4 = idx & 31;
        *(short4*)&wt[n * LDP + c4 * 4] = ((const short4*)w2t)[idx];
    }
    __syncthreads();
    int wave = t >> 6, lane = t & 63;
    int quad = lane >> 4, c = lane & 15;
    int m0 = wave * 16;
    f32x4 acc[4] = {};
    #pragma unroll
    for (int kc = 0; kc < 4; ++kc) {
        short8v av = *(const short8v*)&xs[(m0 + c) * LDP + kc * 32 + quad * 8];
        #pragma unroll
        for (int nt = 0; nt < 4; ++nt) {
            short8v b = *(const short8v*)&wt[(nt * 16 + c) * LDP + kc * 32 + quad * 8];
            acc[nt] = __builtin_amdgcn_mfma_f32_16x16x32_bf16(av, b, acc[nt], 0, 0, 0);
        }
    }
    #pragma unroll
    for (int nt = 0; nt < 4; ++nt)
        #pragma unroll
        for (int r = 0; r < 4; ++r) {
            int row = row0 + m0 + quad * 4 + r;
            if (row < nrows) h2[(size_t)row * 64 + nt * 16 + c] = f2bf(acc[nt][r]);
        }
}

// pull aggregation, 128 bf16 feats: one wave/node, lane owns feats [2l,2l+1].
__global__ __launch_bounds__(256) void k_pull128(const unsigned short* __restrict__ h,
                                                 const int* __restrict__ row_ptr,
                                                 const int* __restrict__ deg,
                                                 const int2* __restrict__ csr8,
                                                 const float* __restrict__ dinv,
                                                 float* __restrict__ agg, int n) {
    int wave = (blockIdx.x * 256 + threadIdx.x) >> 6;
    int lane = threadIdx.x & 63;
    if (wave >= n) return;
    int i = __builtin_amdgcn_readfirstlane(wave);
    float di = dinv[i];
    float2 acc;
    {
        unsigned u = ((const unsigned*)(h + (size_t)i * 128))[lane];
        float w = di * di;
        acc.x = __uint_as_float(u << 16) * w;
        acc.y = __uint_as_float(u & 0xffff0000u) * w;
    }
    int beg = row_ptr[i];
    int cnt = deg[i];
    int k = 0;
    for (; k + 4 <= cnt; k += 4) {
        int2 e0 = csr8[beg + k + 0];
        int2 e1 = csr8[beg + k + 1];
        int2 e2 = csr8[beg + k + 2];
        int2 e3 = csr8[beg + k + 3];
        float n0 = di * __int_as_float(e0.y), n1 = di * __int_as_float(e1.y);
        float n2 = di * __int_as_float(e2.y), n3 = di * __int_as_float(e3.y);
        unsigned u0 = ((const unsigned*)(h + (size_t)e0.x * 128))[lane];
        unsigned u1 = ((const unsigned*)(h + (size_t)e1.x * 128))[lane];
        unsigned u2 = ((const unsigned*)(h + (size_t)e2.x * 128))[lane];
        unsigned u3 = ((const unsigned*)(h + (size_t)e3.x * 128))[lane];
        acc.x += __uint_as_float(u0 << 16) * n0 + __uint_as_float(u1 << 16) * n1
               + __uint_as_float(u2 << 16) * n2 + __uint_as_float(u3 << 16) * n3;
        acc.y += __uint_as_float(u0 & 0xffff0000u) * n0 + __uint_as_float(u1 & 0xffff0000u) * n1
               + __uint_as_float(u2 & 0xffff0000u) * n2 + __uint_as_float(u3 & 0xffff0000u) * n3;
    }
    for (; k < cnt; ++k) {
        int2 e = csr8[beg + k];
        float nrm = di * __int_as_float(e.y);
        unsigned u = ((const unsigned*)(h + (size_t)e.x * 128))[lane];
        acc.x += __uint_as_float(u << 16) * nrm;
        acc.y += __uint_as_float(u & 0xffff0000u) * nrm;
    }
    ((float2*)&agg[(size_t)i * 128])[lane] = acc;
}

// pull aggregation, 64 bf16 feats, fused +b2 -> out (fp32)
__global__ __launch_bounds__(256) void k_pull64(const unsigned short* __restrict__ h,
                                                const int* __restrict__ row_ptr,
                                                const int* __restrict__ deg,
                                                const int2* __restrict__ csr8,
                                                const float* __restrict__ dinv,
                                                const float* __restrict__ b2,
                                                float* __restrict__ out, int n) {
    int wave = (blockIdx.x * 256 + threadIdx.x) >> 6;
    int lane = threadIdx.x & 63;
    if (wave >= n) return;
    int i = __builtin_amdgcn_readfirstlane(wave);
    float di = dinv[i];
    float acc = bfbits(h[(size_t)i * 64 + lane]) * di * di;
    int beg = row_ptr[i];
    int cnt = deg[i];
    int k = 0;
    for (; k + 4 <= cnt; k += 4) {
        int2 e0 = csr8[beg + k + 0];
        int2 e1 = csr8[beg + k + 1];
        int2 e2 = csr8[beg + k + 2];
        int2 e3 = csr8[beg + k + 3];
        float n0 = di * __int_as_float(e0.y), n1 = di * __int_as_float(e1.y);
        float n2 = di * __int_as_float(e2.y), n3 = di * __int_as_float(e3.y);
        acc += bfbits(h[(size_t)e0.x * 64 + lane]) * n0
             + bfbits(h[(size_t)e1.x * 64 + lane]) * n1
             + bfbits(h[(size_t)e2.x * 64 + lane]) * n2
             + bfbits(h[(size_t)e3.x * 64 + lane]) * n3;
    }
    for (; k < cnt; ++k) {
        int2 e = csr8[beg + k];
        acc += bfbits(h[(size_t)e.x * 64 + lane]) * (di * __int_as_float(e.y));
    }
    out[(size_t)i * 64 + lane] = acc + b2[lane];
}

extern "C" void kernel_launch(void* const* d_in, const int* in_sizes, int n_in,
                              void* d_out, int out_size, void* d_ws, size_t ws_size,
                              hipStream_t stream) {
    const float* x  = (const float*)d_in[0];
    const int*   ei = (const int*)d_in[1];
    const float* W1 = (const float*)d_in[2];
    const float* b1 = (const float*)d_in[3];
    const float* W2 = (const float*)d_in[4];
    const float* b2 = (const float*)d_in[5];
    float* out = (float*)d_out;

    const int N = in_sizes[0] / 128;
    const int E = in_sizes[1] / 2;
    const int* src = ei;
    const int* dst = ei + E;
    const int nbuck = (N + BSIZE - 1) >> BSHIFT;       // 196 for N=100000

    float* dinv    = (float*)d_ws;                     // N
    int*   deg     = (int*)(dinv + N);                 // N
    int*   row_ptr = deg + N;                          // N
    int*   bcnt    = row_ptr + N;                      // 256
    int*   bcur    = bcnt + 256;                       // 256
    int*   bbase   = bcur + 256;                       // 256
    short* w1t     = (short*)(bbase + 256);            // 128*128
    short* w2t     = w1t + 128 * 128;                  // 64*128
    int2*  csr8    = (int2*)(w2t + 64 * 128);          // E int2
    short* bufH    = (short*)(csr8 + E);               // N*128 bf16
    float* bufA    = (float*)(bufH + (size_t)N * 128); // N*128 f32
    int2*  ebuf    = (int2*)bufA;                      // E int2 (aliases bufA;
                                                       // last ebuf use precedes
                                                       // first bufA write)

    const int ntile = (E + 4095) / 4096;               // phase-A tiles

    // ---- bucketed CSR build (per-node atomics all in LDS) ----
    k_zero<<<1, 256, 0, stream>>>(bcnt, nbuck);
    k_bhist<<<ntile, 256, 0, stream>>>(dst, bcnt, E, nbuck);
    k_bscan<<<1, 256, 0, stream>>>(bcnt, bcur, bbase, nbuck);
    k_bucket<<<ntile, 256, 0, stream>>>(src, dst, bcur, ebuf, E, nbuck);
    k_bdeg<<<nbuck, BSIZE, 0, stream>>>(ebuf, bbase, bcnt, deg, row_ptr, dinv, N);
    k_bscatter<<<nbuck, BSIZE, 0, stream>>>(ebuf, bbase, bcnt, row_ptr, dinv, csr8, N);

    k_prepW<<<96, 256, 0, stream>>>(W1, W2, w1t, w2t);

    // ---- layer 1 ----
    k_gemm1<<<(N + 63) / 64, 256, 0, stream>>>(x, w1t, bufH, N);
    k_pull128<<<(N + 3) / 4, 256, 0, stream>>>((const unsigned short*)bufH, row_ptr, deg, csr8, dinv, bufA, N);

    // ---- layer 2 ----
    k_gemm2<<<(N + 63) / 64, 256, 0, stream>>>(bufA, b1, w2t, bufH, N);
    k_pull64<<<(N + 3) / 4, 256, 0, stream>>>((const unsigned short*)bufH, row_ptr, deg, csr8, dinv, b2, out, N);
}

// Round 8
// 304.513 us; speedup vs baseline: 4.5071x; 1.0858x over previous
//
#include <hip/hip_runtime.h>
#include <hip/hip_bf16.h>

// GCN 2-layer forward, fp32 I/O. Fixed-capacity bucketed CSR build (all
// per-node atomics in LDS, no global histogram/scan), bf16 h AND agg1
// storage, {src,dinv} fused CSR entries, MFMA bf16 GEMMs.
// Pipeline:
//  1) k_init: bcur[b] = b*CAP
//  2) k_bucket: partition {src,dst} by dst>>9 into padded ebuf (LDS tile)
//  3) k_bdeg:  per-bucket LDS hist -> deg, dinv, row_ptr (LDS scan)
//  4) k_bscatter: per-bucket LDS-cursor scatter -> csr8 = {src, dinv[src]}
//  5) h1 = x @ W1 -> bf16                          (k_gemm1, MFMA)
//  6) agg1 = D^-1/2 (A+I) D^-1/2 h1 -> bf16        (k_pull128)
//  7) h2 = relu(agg1 + b1) @ W2 -> bf16            (k_gemm2, MFMA)
//  8) out = aggregate(h2) + b2 -> fp32             (k_pull64)

typedef short short8v __attribute__((ext_vector_type(8)));   // 8 bf16 (4 VGPRs)
typedef float f32x4   __attribute__((ext_vector_type(4)));   // MFMA acc

#define BSHIFT 9           // bucket = dst >> 9 (span 512 nodes)
#define BSIZE  512
#define CAPSH  14          // per-bucket capacity 16384 (mean 8163, >40 sigma)
#define CAP    (1 << CAPSH)

// RNE fp32 -> bf16 (finite inputs)
__device__ __forceinline__ short f2bf(float f) {
    unsigned u = __float_as_uint(f);
    return (short)((u + 0x7fffu + ((u >> 16) & 1u)) >> 16);
}
__device__ __forceinline__ float bfbits(unsigned short s) {
    return __uint_as_float((unsigned)s << 16);
}
__device__ __forceinline__ unsigned pack2bf(float a, float b) {
    return (unsigned)(unsigned short)f2bf(a) | ((unsigned)(unsigned short)f2bf(b) << 16);
}

__global__ void k_init(int* __restrict__ bcur, int nbuck) {
    int i = threadIdx.x;
    if (i < nbuck) bcur[i] = i << CAPSH;
}

// ---- partition edges by dst-bucket into padded ebuf; edge tile in LDS ----
__global__ __launch_bounds__(256) void k_bucket(const int* __restrict__ src,
                                                const int* __restrict__ dst,
                                                int* __restrict__ bcur,
                                                int2* __restrict__ ebuf,
                                                int E, int nbuck) {
    __shared__ int sdst[4096];
    __shared__ int ssrc[4096];
    __shared__ int hist[256];
    __shared__ int base[256];
    int t = threadIdx.x;
    int e0 = blockIdx.x * 4096;
    for (int i = t; i < nbuck; i += 256) hist[i] = 0;
    for (int i = 0; i < 16; ++i) {                  // single global read
        int k = i * 256 + t;
        int e = e0 + k;
        sdst[k] = (e < E) ? dst[e] : -1;
        ssrc[k] = (e < E) ? src[e] : 0;
    }
    __syncthreads();
    for (int i = 0; i < 16; ++i) {                  // pass 1: LDS histogram
        int d = sdst[i * 256 + t];
        if (d >= 0) atomicAdd(&hist[d >> BSHIFT], 1);
    }
    __syncthreads();
    for (int b = t; b < nbuck; b += 256) {          // pass 2: reserve chunks
        int c = hist[b];
        base[b] = c ? atomicAdd(&bcur[b], c) : 0;
        hist[b] = 0;
    }
    __syncthreads();
    for (int i = 0; i < 16; ++i) {                  // pass 3: grouped writes
        int k = i * 256 + t;
        int d = sdst[k];
        if (d >= 0) {
            int bk = d >> BSHIFT;
            int off = atomicAdd(&hist[bk], 1);
            ebuf[base[bk] + off] = make_int2(ssrc[k], d);
        }
    }
}

// ---- per-bucket: LDS hist -> deg, dinv; LDS scan -> row_ptr ----
__global__ __launch_bounds__(BSIZE) void k_bdeg(const int2* __restrict__ ebuf,
                                                const int* __restrict__ bcur,
                                                int* __restrict__ deg,
                                                int* __restrict__ row_ptr,
                                                float* __restrict__ dinv, int n) {
    __shared__ int hist[BSIZE];
    __shared__ int s[BSIZE];
    int b = blockIdx.x;
    int t = threadIdx.x;
    hist[t] = 0;
    __syncthreads();
    int base = b << CAPSH;
    int cnt  = bcur[b] - base;
    int lo = b << BSHIFT;
    for (int k = t; k < cnt; k += BSIZE)
        atomicAdd(&hist[ebuf[base + k].y - lo], 1);   // LDS atomic only
    __syncthreads();
    int v = hist[t];
    s[t] = v;
    __syncthreads();
    for (int off = 1; off < BSIZE; off <<= 1) {
        int add = (t >= off) ? s[t - off] : 0;
        __syncthreads();
        s[t] += add;
        __syncthreads();
    }
    int node = lo + t;
    if (node < n) {
        deg[node]     = v;
        row_ptr[node] = base + s[t] - v;              // padded-CSR offset
        dinv[node]    = rsqrtf((float)(v + 1));
    }
}

// ---- per-bucket: scatter ebuf -> csr8 with LDS cursors ----
__global__ __launch_bounds__(BSIZE) void k_bscatter(const int2* __restrict__ ebuf,
                                                    const int* __restrict__ bcur,
                                                    const int* __restrict__ row_ptr,
                                                    const float* __restrict__ dinv,
                                                    int2* __restrict__ csr8, int n) {
    __shared__ int cur[BSIZE];
    int b = blockIdx.x;
    int t = threadIdx.x;
    int lo = b << BSHIFT;
    int node = lo + t;
    cur[t] = (node < n) ? row_ptr[node] : 0;
    __syncthreads();
    int base = b << CAPSH;
    int cnt  = bcur[b] - base;
    for (int k = t; k < cnt; k += BSIZE) {
        int2 ed = ebuf[base + k];
        int pos = atomicAdd(&cur[ed.y - lo], 1);      // LDS atomic only
        csr8[pos] = make_int2(ed.x, __float_as_int(dinv[ed.x]));
    }
}

// W1[128k][128n] -> w1t[n][k] bf16 ; W2[128k][64n] -> w2t[n][k] bf16
__global__ void k_prepW(const float* __restrict__ W1, const float* __restrict__ W2,
                        short* __restrict__ w1t, short* __restrict__ w2t) {
    int i = blockIdx.x * blockDim.x + threadIdx.x;
    if (i < 128 * 128) {
        int n = i >> 7, k = i & 127;
        w1t[i] = f2bf(W1[k * 128 + n]);
    } else if (i < 128 * 128 + 64 * 128) {
        int j = i - 128 * 128;
        int n = j >> 7, k = j & 127;
        w2t[j] = f2bf(W2[k * 64 + n]);
    }
}

// ---- MFMA GEMM1: h[64rows/block,128] = bf16(x) @ bf16(W1), 256 thr ----
#define LDP 136
__global__ __launch_bounds__(256) void k_gemm1(const float* __restrict__ x,
                                               const short* __restrict__ w1t,
                                               short* __restrict__ h, int nrows) {
    __shared__ short xs[64 * LDP];
    __shared__ short wt[128 * LDP];
    int t = threadIdx.x;
    int row0 = blockIdx.x * 64;
    for (int i = 0; i < 16; ++i) {
        int idx = t + i * 256;
        int r = idx >> 5, c4 = idx & 31;
        float4 v = make_float4(0.f, 0.f, 0.f, 0.f);
        if (row0 + r < nrows) v = ((const float4*)x)[(size_t)(row0 + r) * 32 + c4];
        short4 o = make_short4(f2bf(v.x), f2bf(v.y), f2bf(v.z), f2bf(v.w));
        *(short4*)&xs[r * LDP + c4 * 4] = o;
    }
    for (int i = 0; i < 16; ++i) {
        int idx = t + i * 256;
        int n = idx >> 5, c4 = idx & 31;
        *(short4*)&wt[n * LDP + c4 * 4] = ((const short4*)w1t)[idx];
    }
    __syncthreads();
    int wave = t >> 6, lane = t & 63;
    int quad = lane >> 4, c = lane & 15;
    int m0 = wave * 16;
    f32x4 acc[8] = {};
    #pragma unroll
    for (int kc = 0; kc < 4; ++kc) {
        short8v a = *(const short8v*)&xs[(m0 + c) * LDP + kc * 32 + quad * 8];
        #pragma unroll
        for (int nt = 0; nt < 8; ++nt) {
            short8v b = *(const short8v*)&wt[(nt * 16 + c) * LDP + kc * 32 + quad * 8];
            acc[nt] = __builtin_amdgcn_mfma_f32_16x16x32_bf16(a, b, acc[nt], 0, 0, 0);
        }
    }
    #pragma unroll
    for (int nt = 0; nt < 8; ++nt)
        #pragma unroll
        for (int r = 0; r < 4; ++r) {
            int row = row0 + m0 + quad * 4 + r;
            if (row < nrows) h[(size_t)row * 128 + nt * 16 + c] = f2bf(acc[nt][r]);
        }
}

// ---- MFMA GEMM2: h2[64rows,64] = bf16(relu(bf16agg + b1)) @ bf16(W2) ----
__global__ __launch_bounds__(256) void k_gemm2(const unsigned* __restrict__ aggb, // bf16x2
                                               const float* __restrict__ b1,
                                               const short* __restrict__ w2t,
                                               short* __restrict__ h2, int nrows) {
    __shared__ short xs[64 * LDP];
    __shared__ short wt[64 * LDP];
    int t = threadIdx.x;
    int row0 = blockIdx.x * 64;
    for (int i = 0; i < 16; ++i) {                    // 64 rows x 64 bf16-pairs
        int idx = t + i * 256;
        int r = idx >> 6, cp = idx & 63;
        unsigned o = 0;
        if (row0 + r < nrows) {
            unsigned u = aggb[(size_t)(row0 + r) * 64 + cp];
            float2 bb = ((const float2*)b1)[cp];
            float vx = fmaxf(__uint_as_float(u << 16) + bb.x, 0.f);
            float vy = fmaxf(__uint_as_float(u & 0xffff0000u) + bb.y, 0.f);
            o = pack2bf(vx, vy);
        }
        *(unsigned*)&xs[r * LDP + cp * 2] = o;
    }
    for (int i = 0; i < 8; ++i) {
        int idx = t + i * 256;
        int n = idx >> 5, c4 = idx & 31;
        *(short4*)&wt[n * LDP + c4 * 4] = ((const short4*)w2t)[idx];
    }
    __syncthreads();
    int wave = t >> 6, lane = t & 63;
    int quad = lane >> 4, c = lane & 15;
    int m0 = wave * 16;
    f32x4 acc[4] = {};
    #pragma unroll
    for (int kc = 0; kc < 4; ++kc) {
        short8v av = *(const short8v*)&xs[(m0 + c) * LDP + kc * 32 + quad * 8];
        #pragma unroll
        for (int nt = 0; nt < 4; ++nt) {
            short8v b = *(const short8v*)&wt[(nt * 16 + c) * LDP + kc * 32 + quad * 8];
            acc[nt] = __builtin_amdgcn_mfma_f32_16x16x32_bf16(av, b, acc[nt], 0, 0, 0);
        }
    }
    #pragma unroll
    for (int nt = 0; nt < 4; ++nt)
        #pragma unroll
        for (int r = 0; r < 4; ++r) {
            int row = row0 + m0 + quad * 4 + r;
            if (row < nrows) h2[(size_t)row * 64 + nt * 16 + c] = f2bf(acc[nt][r]);
        }
}

// pull aggregation, 128 bf16 feats -> bf16 agg. One wave/node; 8-wide unroll.
__global__ __launch_bounds__(256) void k_pull128(const unsigned short* __restrict__ h,
                                                 const int* __restrict__ row_ptr,
                                                 const int* __restrict__ deg,
                                                 const int2* __restrict__ csr8,
                                                 const float* __restrict__ dinv,
                                                 unsigned* __restrict__ aggb, int n) {
    int wave = (blockIdx.x * 256 + threadIdx.x) >> 6;
    int lane = threadIdx.x & 63;
    if (wave >= n) return;
    int i = __builtin_amdgcn_readfirstlane(wave);
    float di = dinv[i];
    float2 acc;
    {
        unsigned u = ((const unsigned*)(h + (size_t)i * 128))[lane];
        float w = di * di;
        acc.x = __uint_as_float(u << 16) * w;
        acc.y = __uint_as_float(u & 0xffff0000u) * w;
    }
    int beg = row_ptr[i];
    int cnt = deg[i];
    int k = 0;
    for (; k + 8 <= cnt; k += 8) {
        int2 e[8];
        unsigned u[8];
        #pragma unroll
        for (int j = 0; j < 8; ++j) e[j] = csr8[beg + k + j];
        #pragma unroll
        for (int j = 0; j < 8; ++j)
            u[j] = ((const unsigned*)(h + (size_t)e[j].x * 128))[lane];
        #pragma unroll
        for (int j = 0; j < 8; ++j) {
            float nr = di * __int_as_float(e[j].y);
            acc.x += __uint_as_float(u[j] << 16) * nr;
            acc.y += __uint_as_float(u[j] & 0xffff0000u) * nr;
        }
    }
    for (; k < cnt; ++k) {
        int2 e = csr8[beg + k];
        float nr = di * __int_as_float(e.y);
        unsigned u = ((const unsigned*)(h + (size_t)e.x * 128))[lane];
        acc.x += __uint_as_float(u << 16) * nr;
        acc.y += __uint_as_float(u & 0xffff0000u) * nr;
    }
    aggb[(size_t)i * 64 + lane] = pack2bf(acc.x, acc.y);
}

// pull aggregation, 64 bf16 feats, fused +b2 -> out (fp32). 8-wide unroll.
__global__ __launch_bounds__(256) void k_pull64(const unsigned short* __restrict__ h,
                                                const int* __restrict__ row_ptr,
                                                const int* __restrict__ deg,
                                                const int2* __restrict__ csr8,
                                                const float* __restrict__ dinv,
                                                const float* __restrict__ b2,
                                                float* __restrict__ out, int n) {
    int wave = (blockIdx.x * 256 + threadIdx.x) >> 6;
    int lane = threadIdx.x & 63;
    if (wave >= n) return;
    int i = __builtin_amdgcn_readfirstlane(wave);
    float di = dinv[i];
    float acc = bfbits(h[(size_t)i * 64 + lane]) * di * di;
    int beg = row_ptr[i];
    int cnt = deg[i];
    int k = 0;
    for (; k + 8 <= cnt; k += 8) {
        int2 e[8];
        unsigned short u[8];
        #pragma unroll
        for (int j = 0; j < 8; ++j) e[j] = csr8[beg + k + j];
        #pragma unroll
        for (int j = 0; j < 8; ++j) u[j] = h[(size_t)e[j].x * 64 + lane];
        #pragma unroll
        for (int j = 0; j < 8; ++j)
            acc += bfbits(u[j]) * (di * __int_as_float(e[j].y));
    }
    for (; k < cnt; ++k) {
        int2 e = csr8[beg + k];
        acc += bfbits(h[(size_t)e.x * 64 + lane]) * (di * __int_as_float(e.y));
    }
    out[(size_t)i * 64 + lane] = acc + b2[lane];
}

extern "C" void kernel_launch(void* const* d_in, const int* in_sizes, int n_in,
                              void* d_out, int out_size, void* d_ws, size_t ws_size,
                              hipStream_t stream) {
    const float* x  = (const float*)d_in[0];
    const int*   ei = (const int*)d_in[1];
    const float* W1 = (const float*)d_in[2];
    const float* b1 = (const float*)d_in[3];
    const float* W2 = (const float*)d_in[4];
    const float* b2 = (const float*)d_in[5];
    float* out = (float*)d_out;

    const int N = in_sizes[0] / 128;
    const int E = in_sizes[1] / 2;
    const int* src = ei;
    const int* dst = ei + E;
    const int nbuck = (N + BSIZE - 1) >> BSHIFT;        // 196 for N=100000
    const size_t capE = (size_t)nbuck << CAPSH;         // padded edge capacity

    float* dinv    = (float*)d_ws;                      // N
    int*   deg     = (int*)(dinv + N);                  // N
    int*   row_ptr = deg + N;                           // N
    int*   bcur    = row_ptr + N;                       // 256
    short* w1t     = (short*)(bcur + 256);              // 128*128
    short* w2t     = w1t + 128 * 128;                   // 64*128
    int2*  csr8    = (int2*)(w2t + 64 * 128);           // capE (25.7 MB)
    short* bufH    = (short*)(csr8 + capE);             // N*128 bf16 (h1)
    short* bufH2   = bufH + (size_t)N * 128;            // N*64  bf16 (h2)
    unsigned* aggb = (unsigned*)(bufH2 + (size_t)N * 64); // N*64 bf16x2 (agg1)
    int2*  ebuf    = (int2*)bufH2;                      // capE; aliases bufH2+aggb
                                                        // (ebuf dead before
                                                        //  gemm2/pull128 write)

    const int ntile = (E + 4095) / 4096;

    // ---- bucketed CSR build (per-node atomics all in LDS) ----
    k_init<<<1, 256, 0, stream>>>(bcur, nbuck);
    k_bucket<<<ntile, 256, 0, stream>>>(src, dst, bcur, ebuf, E, nbuck);
    k_bdeg<<<nbuck, BSIZE, 0, stream>>>(ebuf, bcur, deg, row_ptr, dinv, N);
    k_bscatter<<<nbuck, BSIZE, 0, stream>>>(ebuf, bcur, row_ptr, dinv, csr8, N);

    k_prepW<<<96, 256, 0, stream>>>(W1, W2, w1t, w2t);

    // ---- layer 1 ----
    k_gemm1<<<(N + 63) / 64, 256, 0, stream>>>(x, w1t, bufH, N);
    k_pull128<<<(N + 3) / 4, 256, 0, stream>>>((const unsigned short*)bufH, row_ptr, deg, csr8, dinv, aggb, N);

    // ---- layer 2 ----
    k_gemm2<<<(N + 63) / 64, 256, 0, stream>>>(aggb, b1, w2t, bufH2, N);
    k_pull64<<<(N + 3) / 4, 256, 0, stream>>>((const unsigned short*)bufH2, row_ptr, deg, csr8, dinv, b2, out, N);
}

// Round 9
// 304.013 us; speedup vs baseline: 4.5145x; 1.0016x over previous
//
#include <hip/hip_runtime.h>
#include <hip/hip_bf16.h>

// GCN 2-layer forward, fp32 I/O. Fixed-capacity bucketed CSR build (all
// per-node atomics in LDS), bf16 h + agg1 storage, {src,dinv} fused CSR,
// MFMA bf16 GEMMs, two-nodes-per-wave pull aggregation (half-wave gathers
// double the edges-in-flight per vector load).
// Pipeline:
//  1) k_init: bcur[b] = b*CAP
//  2) k_bucket: partition {src,dst} by dst>>9 into padded ebuf (LDS tile)
//  3) k_bdeg:  per-bucket LDS hist -> deg, dinv, row_ptr (LDS scan)
//  4) k_bscatter: per-bucket LDS-cursor scatter -> csr8 = {src, dinv[src]}
//  5) h1 = x @ W1 -> bf16                          (k_gemm1, MFMA)
//  6) agg1 = D^-1/2 (A+I) D^-1/2 h1 -> bf16        (k_pull128)
//  7) h2 = relu(agg1 + b1) @ W2 -> bf16            (k_gemm2, MFMA)
//  8) out = aggregate(h2) + b2 -> fp32             (k_pull64)

typedef short short8v __attribute__((ext_vector_type(8)));   // 8 bf16 (4 VGPRs)
typedef float f32x4   __attribute__((ext_vector_type(4)));   // MFMA acc

#define BSHIFT 9           // bucket = dst >> 9 (span 512 nodes)
#define BSIZE  512
#define CAPSH  14          // per-bucket capacity 16384 (mean 8163, >40 sigma)
#define CAP    (1 << CAPSH)

// RNE fp32 -> bf16 (finite inputs)
__device__ __forceinline__ short f2bf(float f) {
    unsigned u = __float_as_uint(f);
    return (short)((u + 0x7fffu + ((u >> 16) & 1u)) >> 16);
}
__device__ __forceinline__ float bfbits(unsigned short s) {
    return __uint_as_float((unsigned)s << 16);
}
__device__ __forceinline__ unsigned pack2bf(float a, float b) {
    return (unsigned)(unsigned short)f2bf(a) | ((unsigned)(unsigned short)f2bf(b) << 16);
}
__device__ __forceinline__ float bflo(unsigned u) { return __uint_as_float(u << 16); }
__device__ __forceinline__ float bfhi(unsigned u) { return __uint_as_float(u & 0xffff0000u); }

__global__ void k_init(int* __restrict__ bcur, int nbuck) {
    int i = threadIdx.x;
    if (i < nbuck) bcur[i] = i << CAPSH;
}

// ---- partition edges by dst-bucket into padded ebuf; edge tile in LDS ----
__global__ __launch_bounds__(256) void k_bucket(const int* __restrict__ src,
                                                const int* __restrict__ dst,
                                                int* __restrict__ bcur,
                                                int2* __restrict__ ebuf,
                                                int E, int nbuck) {
    __shared__ int sdst[4096];
    __shared__ int ssrc[4096];
    __shared__ int hist[256];
    __shared__ int base[256];
    int t = threadIdx.x;
    int e0 = blockIdx.x * 4096;
    for (int i = t; i < nbuck; i += 256) hist[i] = 0;
    for (int i = 0; i < 16; ++i) {                  // single global read
        int k = i * 256 + t;
        int e = e0 + k;
        sdst[k] = (e < E) ? dst[e] : -1;
        ssrc[k] = (e < E) ? src[e] : 0;
    }
    __syncthreads();
    for (int i = 0; i < 16; ++i) {                  // pass 1: LDS histogram
        int d = sdst[i * 256 + t];
        if (d >= 0) atomicAdd(&hist[d >> BSHIFT], 1);
    }
    __syncthreads();
    for (int b = t; b < nbuck; b += 256) {          // pass 2: reserve chunks
        int c = hist[b];
        base[b] = c ? atomicAdd(&bcur[b], c) : 0;
        hist[b] = 0;
    }
    __syncthreads();
    for (int i = 0; i < 16; ++i) {                  // pass 3: grouped writes
        int k = i * 256 + t;
        int d = sdst[k];
        if (d >= 0) {
            int bk = d >> BSHIFT;
            int off = atomicAdd(&hist[bk], 1);
            ebuf[base[bk] + off] = make_int2(ssrc[k], d);
        }
    }
}

// ---- per-bucket: LDS hist -> deg, dinv; LDS scan -> row_ptr ----
__global__ __launch_bounds__(BSIZE) void k_bdeg(const int2* __restrict__ ebuf,
                                                const int* __restrict__ bcur,
                                                int* __restrict__ deg,
                                                int* __restrict__ row_ptr,
                                                float* __restrict__ dinv, int n) {
    __shared__ int hist[BSIZE];
    __shared__ int s[BSIZE];
    int b = blockIdx.x;
    int t = threadIdx.x;
    hist[t] = 0;
    __syncthreads();
    int base = b << CAPSH;
    int cnt  = bcur[b] - base;
    int lo = b << BSHIFT;
    for (int k = t; k < cnt; k += BSIZE)
        atomicAdd(&hist[ebuf[base + k].y - lo], 1);   // LDS atomic only
    __syncthreads();
    int v = hist[t];
    s[t] = v;
    __syncthreads();
    for (int off = 1; off < BSIZE; off <<= 1) {
        int add = (t >= off) ? s[t - off] : 0;
        __syncthreads();
        s[t] += add;
        __syncthreads();
    }
    int node = lo + t;
    if (node < n) {
        deg[node]     = v;
        row_ptr[node] = base + s[t] - v;              // padded-CSR offset
        dinv[node]    = rsqrtf((float)(v + 1));
    }
}

// ---- per-bucket: scatter ebuf -> csr8 with LDS cursors ----
__global__ __launch_bounds__(BSIZE) void k_bscatter(const int2* __restrict__ ebuf,
                                                    const int* __restrict__ bcur,
                                                    const int* __restrict__ row_ptr,
                                                    const float* __restrict__ dinv,
                                                    int2* __restrict__ csr8, int n) {
    __shared__ int cur[BSIZE];
    int b = blockIdx.x;
    int t = threadIdx.x;
    int lo = b << BSHIFT;
    int node = lo + t;
    cur[t] = (node < n) ? row_ptr[node] : 0;
    __syncthreads();
    int base = b << CAPSH;
    int cnt  = bcur[b] - base;
    for (int k = t; k < cnt; k += BSIZE) {
        int2 ed = ebuf[base + k];
        int pos = atomicAdd(&cur[ed.y - lo], 1);      // LDS atomic only
        csr8[pos] = make_int2(ed.x, __float_as_int(dinv[ed.x]));
    }
}

// W1[128k][128n] -> w1t[n][k] bf16 ; W2[128k][64n] -> w2t[n][k] bf16
__global__ void k_prepW(const float* __restrict__ W1, const float* __restrict__ W2,
                        short* __restrict__ w1t, short* __restrict__ w2t) {
    int i = blockIdx.x * blockDim.x + threadIdx.x;
    if (i < 128 * 128) {
        int n = i >> 7, k = i & 127;
        w1t[i] = f2bf(W1[k * 128 + n]);
    } else if (i < 128 * 128 + 64 * 128) {
        int j = i - 128 * 128;
        int n = j >> 7, k = j & 127;
        w2t[j] = f2bf(W2[k * 64 + n]);
    }
}

// ---- MFMA GEMM1: h[64rows/block,128] = bf16(x) @ bf16(W1), 256 thr ----
#define LDP 136
__global__ __launch_bounds__(256) void k_gemm1(const float* __restrict__ x,
                                               const short* __restrict__ w1t,
                                               short* __restrict__ h, int nrows) {
    __shared__ short xs[64 * LDP];
    __shared__ short wt[128 * LDP];
    int t = threadIdx.x;
    int row0 = blockIdx.x * 64;
    for (int i = 0; i < 16; ++i) {
        int idx = t + i * 256;
        int r = idx >> 5, c4 = idx & 31;
        float4 v = make_float4(0.f, 0.f, 0.f, 0.f);
        if (row0 + r < nrows) v = ((const float4*)x)[(size_t)(row0 + r) * 32 + c4];
        short4 o = make_short4(f2bf(v.x), f2bf(v.y), f2bf(v.z), f2bf(v.w));
        *(short4*)&xs[r * LDP + c4 * 4] = o;
    }
    for (int i = 0; i < 16; ++i) {
        int idx = t + i * 256;
        int n = idx >> 5, c4 = idx & 31;
        *(short4*)&wt[n * LDP + c4 * 4] = ((const short4*)w1t)[idx];
    }
    __syncthreads();
    int wave = t >> 6, lane = t & 63;
    int quad = lane >> 4, c = lane & 15;
    int m0 = wave * 16;
    f32x4 acc[8] = {};
    #pragma unroll
    for (int kc = 0; kc < 4; ++kc) {
        short8v a = *(const short8v*)&xs[(m0 + c) * LDP + kc * 32 + quad * 8];
        #pragma unroll
        for (int nt = 0; nt < 8; ++nt) {
            short8v b = *(const short8v*)&wt[(nt * 16 + c) * LDP + kc * 32 + quad * 8];
            acc[nt] = __builtin_amdgcn_mfma_f32_16x16x32_bf16(a, b, acc[nt], 0, 0, 0);
        }
    }
    #pragma unroll
    for (int nt = 0; nt < 8; ++nt)
        #pragma unroll
        for (int r = 0; r < 4; ++r) {
            int row = row0 + m0 + quad * 4 + r;
            if (row < nrows) h[(size_t)row * 128 + nt * 16 + c] = f2bf(acc[nt][r]);
        }
}

// ---- MFMA GEMM2: h2[64rows,64] = bf16(relu(bf16agg + b1)) @ bf16(W2) ----
__global__ __launch_bounds__(256) void k_gemm2(const unsigned* __restrict__ aggb, // bf16x2
                                               const float* __restrict__ b1,
                                               const short* __restrict__ w2t,
                                               short* __restrict__ h2, int nrows) {
    __shared__ short xs[64 * LDP];
    __shared__ short wt[64 * LDP];
    int t = threadIdx.x;
    int row0 = blockIdx.x * 64;
    for (int i = 0; i < 16; ++i) {                    // 64 rows x 64 bf16-pairs
        int idx = t + i * 256;
        int r = idx >> 6, cp = idx & 63;
        unsigned o = 0;
        if (row0 + r < nrows) {
            unsigned u = aggb[(size_t)(row0 + r) * 64 + cp];
            float2 bb = ((const float2*)b1)[cp];
            float vx = fmaxf(bflo(u) + bb.x, 0.f);
            float vy = fmaxf(bfhi(u) + bb.y, 0.f);
            o = pack2bf(vx, vy);
        }
        *(unsigned*)&xs[r * LDP + cp * 2] = o;
    }
    for (int i = 0; i < 8; ++i) {
        int idx = t + i * 256;
        int n = idx >> 5, c4 = idx & 31;
        *(short4*)&wt[n * LDP + c4 * 4] = ((const short4*)w2t)[idx];
    }
    __syncthreads();
    int wave = t >> 6, lane = t & 63;
    int quad = lane >> 4, c = lane & 15;
    int m0 = wave * 16;
    f32x4 acc[4] = {};
    #pragma unroll
    for (int kc = 0; kc < 4; ++kc) {
        short8v av = *(const short8v*)&xs[(m0 + c) * LDP + kc * 32 + quad * 8];
        #pragma unroll
        for (int nt = 0; nt < 4; ++nt) {
            short8v b = *(const short8v*)&wt[(nt * 16 + c) * LDP + kc * 32 + quad * 8];
            acc[nt] = __builtin_amdgcn_mfma_f32_16x16x32_bf16(av, b, acc[nt], 0, 0, 0);
        }
    }
    #pragma unroll
    for (int nt = 0; nt < 4; ++nt)
        #pragma unroll
        for (int r = 0; r < 4; ++r) {
            int row = row0 + m0 + quad * 4 + r;
            if (row < nrows) h2[(size_t)row * 64 + nt * 16 + c] = f2bf(acc[nt][r]);
        }
}

// pull aggregation, 128 bf16 feats -> bf16 agg. TWO nodes per wave:
// half-wave h handles node wave*2+h, lane l in [0,32) owns feats [4l..4l+3]
// (uint2 = 8 B/lane -> 256 B row per half-wave). 8-wide unroll = 16 edges
// in flight per wave.
__global__ __launch_bounds__(256) void k_pull128(const unsigned short* __restrict__ h,
                                                 const int* __restrict__ row_ptr,
                                                 const int* __restrict__ deg,
                                                 const int2* __restrict__ csr8,
                                                 const float* __restrict__ dinv,
                                                 unsigned* __restrict__ aggb, int n) {
    int wave = (blockIdx.x * 256 + threadIdx.x) >> 6;
    int lane = threadIdx.x & 63;
    int half = lane >> 5;
    int l    = lane & 31;
    int i = wave * 2 + half;
    if (i >= n) return;
    float di = dinv[i];
    float4 acc;
    {
        uint2 u2 = ((const uint2*)(h + (size_t)i * 128))[l];
        float w = di * di;
        acc.x = bflo(u2.x) * w; acc.y = bfhi(u2.x) * w;
        acc.z = bflo(u2.y) * w; acc.w = bfhi(u2.y) * w;
    }
    int beg = row_ptr[i];
    int cnt = deg[i];
    int k = 0;
    for (; k + 8 <= cnt; k += 8) {
        int2 e[8];
        uint2 g[8];
        #pragma unroll
        for (int j = 0; j < 8; ++j) e[j] = csr8[beg + k + j];
        #pragma unroll
        for (int j = 0; j < 8; ++j)
            g[j] = ((const uint2*)(h + (size_t)e[j].x * 128))[l];
        #pragma unroll
        for (int j = 0; j < 8; ++j) {
            float nr = di * __int_as_float(e[j].y);
            acc.x += bflo(g[j].x) * nr; acc.y += bfhi(g[j].x) * nr;
            acc.z += bflo(g[j].y) * nr; acc.w += bfhi(g[j].y) * nr;
        }
    }
    for (; k < cnt; ++k) {
        int2 e = csr8[beg + k];
        float nr = di * __int_as_float(e.y);
        uint2 g = ((const uint2*)(h + (size_t)e.x * 128))[l];
        acc.x += bflo(g.x) * nr; acc.y += bfhi(g.x) * nr;
        acc.z += bflo(g.y) * nr; acc.w += bfhi(g.y) * nr;
    }
    uint2 o;
    o.x = pack2bf(acc.x, acc.y);
    o.y = pack2bf(acc.z, acc.w);
    ((uint2*)(aggb + (size_t)i * 64))[l] = o;
}

// pull aggregation, 64 bf16 feats, fused +b2 -> out (fp32). TWO nodes/wave:
// lane l owns feats [2l,2l+1] (uint = 4 B/lane -> 128 B row per half-wave).
__global__ __launch_bounds__(256) void k_pull64(const unsigned short* __restrict__ h,
                                                const int* __restrict__ row_ptr,
                                                const int* __restrict__ deg,
                                                const int2* __restrict__ csr8,
                                                const float* __restrict__ dinv,
                                                const float* __restrict__ b2,
                                                float* __restrict__ out, int n) {
    int wave = (blockIdx.x * 256 + threadIdx.x) >> 6;
    int lane = threadIdx.x & 63;
    int half = lane >> 5;
    int l    = lane & 31;
    int i = wave * 2 + half;
    if (i >= n) return;
    float di = dinv[i];
    float2 acc;
    {
        unsigned u = ((const unsigned*)(h + (size_t)i * 64))[l];
        float w = di * di;
        acc.x = bflo(u) * w; acc.y = bfhi(u) * w;
    }
    int beg = row_ptr[i];
    int cnt = deg[i];
    int k = 0;
    for (; k + 8 <= cnt; k += 8) {
        int2 e[8];
        unsigned g[8];
        #pragma unroll
        for (int j = 0; j < 8; ++j) e[j] = csr8[beg + k + j];
        #pragma unroll
        for (int j = 0; j < 8; ++j)
            g[j] = ((const unsigned*)(h + (size_t)e[j].x * 64))[l];
        #pragma unroll
        for (int j = 0; j < 8; ++j) {
            float nr = di * __int_as_float(e[j].y);
            acc.x += bflo(g[j]) * nr; acc.y += bfhi(g[j]) * nr;
        }
    }
    for (; k < cnt; ++k) {
        int2 e = csr8[beg + k];
        float nr = di * __int_as_float(e.y);
        unsigned g = ((const unsigned*)(h + (size_t)e.x * 64))[l];
        acc.x += bflo(g) * nr; acc.y += bfhi(g) * nr;
    }
    float2 bb = ((const float2*)b2)[l];
    ((float2*)(out + (size_t)i * 64))[l] = make_float2(acc.x + bb.x, acc.y + bb.y);
}

extern "C" void kernel_launch(void* const* d_in, const int* in_sizes, int n_in,
                              void* d_out, int out_size, void* d_ws, size_t ws_size,
                              hipStream_t stream) {
    const float* x  = (const float*)d_in[0];
    const int*   ei = (const int*)d_in[1];
    const float* W1 = (const float*)d_in[2];
    const float* b1 = (const float*)d_in[3];
    const float* W2 = (const float*)d_in[4];
    const float* b2 = (const float*)d_in[5];
    float* out = (float*)d_out;

    const int N = in_sizes[0] / 128;
    const int E = in_sizes[1] / 2;
    const int* src = ei;
    const int* dst = ei + E;
    const int nbuck = (N + BSIZE - 1) >> BSHIFT;        // 196 for N=100000
    const size_t capE = (size_t)nbuck << CAPSH;         // padded edge capacity

    float* dinv    = (float*)d_ws;                      // N
    int*   deg     = (int*)(dinv + N);                  // N
    int*   row_ptr = deg + N;                           // N
    int*   bcur    = row_ptr + N;                       // 256
    short* w1t     = (short*)(bcur + 256);              // 128*128
    short* w2t     = w1t + 128 * 128;                   // 64*128
    int2*  csr8    = (int2*)(w2t + 64 * 128);           // capE (25.7 MB)
    short* bufH    = (short*)(csr8 + capE);             // N*128 bf16 (h1)
    short* bufH2   = bufH + (size_t)N * 128;            // N*64  bf16 (h2)
    unsigned* aggb = (unsigned*)(bufH2 + (size_t)N * 64); // N*64 bf16x2 (agg1)
    int2*  ebuf    = (int2*)bufH2;                      // capE; aliases bufH2+aggb
                                                        // (ebuf dead before
                                                        //  gemm2/pull128 write)

    const int ntile = (E + 4095) / 4096;

    // ---- bucketed CSR build (per-node atomics all in LDS) ----
    k_init<<<1, 256, 0, stream>>>(bcur, nbuck);
    k_bucket<<<ntile, 256, 0, stream>>>(src, dst, bcur, ebuf, E, nbuck);
    k_bdeg<<<nbuck, BSIZE, 0, stream>>>(ebuf, bcur, deg, row_ptr, dinv, N);
    k_bscatter<<<nbuck, BSIZE, 0, stream>>>(ebuf, bcur, row_ptr, dinv, csr8, N);

    k_prepW<<<96, 256, 0, stream>>>(W1, W2, w1t, w2t);

    // ---- layer 1 ----
    k_gemm1<<<(N + 63) / 64, 256, 0, stream>>>(x, w1t, bufH, N);
    k_pull128<<<(N + 7) / 8, 256, 0, stream>>>((const unsigned short*)bufH, row_ptr, deg, csr8, dinv, aggb, N);

    // ---- layer 2 ----
    k_gemm2<<<(N + 63) / 64, 256, 0, stream>>>(aggb, b1, w2t, bufH2, N);
    k_pull64<<<(N + 7) / 8, 256, 0, stream>>>((const unsigned short*)bufH2, row_ptr, deg, csr8, dinv, b2, out, N);
}